// Round 22
// baseline (263.480 us; speedup 1.0000x reference)
//
#include <hip/hip_runtime.h>
#include <cstdint>

#define L_SEQ 32400
#define HWSZ  32400
#define MPAD  32512
#define NCH   127
#define NH    4
#define LOG2E 1.4426950408889634f

typedef unsigned short u16;
typedef unsigned int   u32;
typedef __attribute__((ext_vector_type(8))) short short8;
typedef __attribute__((ext_vector_type(4))) float f32x4;

__device__ __forceinline__ float silu_f(float v) {
    float e = __expf(-v);
    return v * __builtin_amdgcn_rcpf(1.f + e);
}
__device__ __forceinline__ float softplus_f(float v) { return v > 20.f ? v : log1pf(__expf(v)); }
__device__ __forceinline__ u16 f2bf(float f) {
    u32 u = __float_as_uint(f);
    u += 0x7FFFu + ((u >> 16) & 1u);
    return (u16)(u >> 16);
}
__device__ __forceinline__ u32 cvtpk(float lo, float hi) {
    u32 r;
    asm("v_cvt_pk_bf16_f32 %0, %1, %2" : "=v"(r) : "v"(lo), "v"(hi));
    return r;
}
__device__ __forceinline__ float bf2f(u32 u) { return __uint_as_float(u << 16); }

// ---------------------------------------------------------------------------
// Transpose x [C][HW] -> xt [pix][C] bf16.
// ---------------------------------------------------------------------------
__launch_bounds__(256)
__global__ void xpose_k(const float* __restrict__ x, u16* __restrict__ xt)
{
    __shared__ u16 tile[256][66];
    const int pix0 = blockIdx.x * 64;
    const int tid = threadIdx.x;
    const int pl = tid & 63, cq = tid >> 6;
    const int pix = pix0 + pl;
    const bool pv = pix < HWSZ;
#pragma unroll 4
    for (int j = 0; j < 64; ++j) {
        int c = cq * 64 + j;
        float v = pv ? x[(size_t)c * HWSZ + pix] : 0.f;
        tile[c][pl] = f2bf(v);
    }
    __syncthreads();
    for (int i = 0; i < 64; ++i) {
        int p2 = pix0 + i;
        if (p2 < HWSZ) xt[(size_t)p2 * 256 + tid] = tile[tid][i];
    }
}

__global__ void zero2_k(u16* __restrict__ p, size_t zstride, int n)
{
    int i = blockIdx.x * 256 + threadIdx.x;
    if (i < n) p[(size_t)blockIdx.y * zstride + i] = 0;
}

__global__ void convpad2_k(const float* __restrict__ s0, const float* __restrict__ s1,
                           u16* __restrict__ dst, int rows, int cols, size_t zstride)
{
    const int z = blockIdx.y;
    const float* __restrict__ src = z ? s1 : s0;
    u16* __restrict__ d = dst + (size_t)z * zstride;
    int r = blockIdx.x;
    for (int c = threadIdx.x; c < cols; c += 256)
        d[(size_t)r * cols + c] = (r < rows) ? f2bf(src[(size_t)r * cols + c]) : (u16)0;
}

// ---------------------------------------------------------------------------
// In-proj GEMM, DEPTH-2 register staging with counted vmcnt(2).
// NFRAG=1 (wf = 32 VGPR, no spill risk), NPANEL=10, G=102 -> grid 1020.
// Per phase: prefetch t+2G into the free buffer; compute tile t from LDS;
// barrier; vmcnt(2) (cur buffer's loads are OLDEST in queue -> retired
// without draining epilogue stores); ds_write cur; barrier; epilogue.
// ---------------------------------------------------------------------------
__launch_bounds__(512, 4)
__global__ void inproj_k(const u16* __restrict__ A, const u16* __restrict__ W,
                         u16* __restrict__ zxb, float* __restrict__ tail)
{
    constexpr int K = 256, KS = 8, G = 102, NPANEL = 10;
    __shared__ u16 As[32 * K];

    const int nwg = NPANEL * G;   // 1020
    const int orig = blockIdx.x;
    const int xcd = orig & 7;
    const int q = nwg >> 3, r = nwg & 7;
    const int wgid = (xcd < r ? xcd * (q + 1) : r * (q + 1) + (xcd - r) * q) + (orig >> 3);
    const int panel = wgid % NPANEL;
    const int t0 = wgid / NPANEL;       // 0..101

    const int tid = threadIdx.x;
    const int lane = tid & 63, wn = tid >> 6;
    const int rl15 = lane & 15, kg = lane >> 4;
    const int col = panel * 128 + wn * 16 + rl15;
    const int NT = MPAD / 32;           // 1016

    short8 wf[KS];
#pragma unroll
    for (int ks = 0; ks < KS; ++ks)
        wf[ks] = *(const short8*)(W + (size_t)col * K + ks * 32 + kg * 8);

    auto loadregs = [&](int t, uint4* st) {
        const u16* src = A + (size_t)t * 32 * K;
#pragma unroll
        for (int i = 0; i < 2; ++i) {
            int ch = i * 512 + tid;
            int row = ch >> 5, sl = ch & 31;
            st[i] = *(const uint4*)(src + (size_t)row * K + sl * 8);
        }
    };
    auto dswrite = [&](uint4* st) {
#pragma unroll
        for (int i = 0; i < 2; ++i) {
            int ch = i * 512 + tid;
            int row = ch >> 5, sl = ch & 31;
            *(uint4*)((char*)As + row * 512 + ((sl ^ (row & 7)) * 16)) = st[i];
        }
    };
    auto compute = [&](f32x4 (&acc)[2]) {
        acc[0] = (f32x4){0.f, 0.f, 0.f, 0.f};
        acc[1] = (f32x4){0.f, 0.f, 0.f, 0.f};
        __builtin_amdgcn_s_setprio(1);
#pragma unroll
        for (int ks = 0; ks < KS; ++ks) {
            int sw0 = (ks * 4 + kg) ^ (rl15 & 7);
            short8 a0 = *(const short8*)((const char*)As + rl15 * 512 + sw0 * 16);
            int row1 = 16 + rl15;
            int sw1 = (ks * 4 + kg) ^ (row1 & 7);
            short8 a1 = *(const short8*)((const char*)As + row1 * 512 + sw1 * 16);
            acc[0] = __builtin_amdgcn_mfma_f32_16x16x32_bf16(a0, wf[ks], acc[0], 0, 0, 0);
            acc[1] = __builtin_amdgcn_mfma_f32_16x16x32_bf16(a1, wf[ks], acc[1], 0, 0, 0);
        }
        __builtin_amdgcn_s_setprio(0);
    };
    auto epilogue = [&](int t, f32x4 (&acc)[2]) {
        const int zp = (col >= 640) ? 1 : 0;
        const int c6 = col - zp * 640;
#pragma unroll
        for (int rr = 0; rr < 2; ++rr) {
#pragma unroll
            for (int ri = 0; ri < 4; ++ri) {
                const int gl = t * 32 + rr * 16 + kg * 4 + ri;
                if (gl >= L_SEQ) continue;
                float v = acc[rr][ri];
                if (c6 < 512) {
                    float s = silu_f(v);
                    zxb[(size_t)zp * L_SEQ * 512 + (size_t)gl * 512 + c6] = (u16)cvtpk(s, s);
                } else if (c6 < 520) {
                    tail[(size_t)zp * L_SEQ * 12 + (size_t)gl * 12 + (c6 - 512)] = silu_f(v);
                } else if (c6 < 524) {
                    tail[(size_t)zp * L_SEQ * 12 + (size_t)gl * 12 + (c6 - 512)] = v;
                }
            }
        }
    };

    uint4 stA[2], stB[2];
    // ---- prologue: LDS <- tile t0; stB <- loads for t0+G ----
    loadregs(t0, stA);
    asm volatile("s_waitcnt vmcnt(0)" ::: "memory");
    dswrite(stA);
    asm volatile("s_waitcnt lgkmcnt(0)" ::: "memory");
    __builtin_amdgcn_sched_barrier(0);
    __builtin_amdgcn_s_barrier();
    loadregs(t0 + G, stB);              // t0+G <= 203 < 1016 always

    int t = t0;
    // ---- peeled first iteration (cur = stB) ----
    {
        loadregs(t0 + 2 * G, stA);      // t0+204 <= 305 < 1016 always
        f32x4 acc[2];
        compute(acc);
        __builtin_amdgcn_s_barrier();
        asm volatile("s_waitcnt vmcnt(2)" ::: "memory");   // stB oldest -> retired
        dswrite(stB);
        asm volatile("s_waitcnt lgkmcnt(0)" ::: "memory");
        __builtin_amdgcn_sched_barrier(0);
        __builtin_amdgcn_s_barrier();
        epilogue(t0, acc);
        t = t0 + G;
    }
    // ---- steady loop; invariant: LDS holds t, "cur" buffer holds t+G ----
    for (;;) {
        {   // cur = stA
            const bool hn2 = (t + 2 * G) < NT;
            if (hn2) loadregs(t + 2 * G, stB);
            f32x4 acc[2];
            compute(acc);
            __builtin_amdgcn_s_barrier();
            const bool hn = (t + G) < NT;
            if (hn) {
                if (hn2) asm volatile("s_waitcnt vmcnt(2)" ::: "memory");
                else     asm volatile("s_waitcnt vmcnt(0)" ::: "memory");
                dswrite(stA);
                asm volatile("s_waitcnt lgkmcnt(0)" ::: "memory");
                __builtin_amdgcn_sched_barrier(0);
            }
            __builtin_amdgcn_s_barrier();
            epilogue(t, acc);
            t += G;
            if (!hn) break;
        }
        {   // cur = stB
            const bool hn2 = (t + 2 * G) < NT;
            if (hn2) loadregs(t + 2 * G, stA);
            f32x4 acc[2];
            compute(acc);
            __builtin_amdgcn_s_barrier();
            const bool hn = (t + G) < NT;
            if (hn) {
                if (hn2) asm volatile("s_waitcnt vmcnt(2)" ::: "memory");
                else     asm volatile("s_waitcnt vmcnt(0)" ::: "memory");
                dswrite(stB);
                asm volatile("s_waitcnt lgkmcnt(0)" ::: "memory");
                __builtin_amdgcn_sched_barrier(0);
            }
            __builtin_amdgcn_s_barrier();
            epilogue(t, acc);
            t += G;
            if (!hn) break;
        }
    }
}

// ---------------------------------------------------------------------------
// Out-proj GEMM with FUSED LayerNorm + transpose epilogue (unchanged).
// ---------------------------------------------------------------------------
template<int G>
__launch_bounds__(1024, 2)
__global__ void wsgemmLN_k(const u16* __restrict__ A, const u16* __restrict__ W,
                           const float* __restrict__ lng, const float* __restrict__ lnb_,
                           float* __restrict__ out)
{
    constexpr int K = 512;
    constexpr int KS = K / 32;
    constexpr int SLOTS = K / 8;
    constexpr int LOADS = (32 * SLOTS) / 1024;
    __shared__ u16 As[32 * K];
    __shared__ float lnb[32][257];
    __shared__ float mu_s[32], rs_s[32];

    const int nwg = G;
    const int orig = blockIdx.x;
    const int xcd = orig & 7;
    const int q = nwg >> 3, r = nwg & 7;
    const int wgid = (xcd < r ? xcd * (q + 1) : r * (q + 1) + (xcd - r) * q) + (orig >> 3);
    const int t0 = wgid;

    const int tid = threadIdx.x;
    const int lane = tid & 63, wn = tid >> 6;
    const int rl15 = lane & 15, kg = lane >> 4;
    const int col = wn * 16 + rl15;
    const int NT = MPAD / 32;

    short8 wf[KS];
#pragma unroll
    for (int ks = 0; ks < KS; ++ks)
        wf[ks] = *(const short8*)(W + (size_t)col * K + ks * 32 + kg * 8);

    auto loadregs = [&](int t, uint4* st) {
        const u16* src = A + (size_t)t * 32 * K;
#pragma unroll
        for (int i = 0; i < LOADS; ++i) {
            int ch = i * 1024 + tid;
            int row = ch >> 6, sl = ch & 63;
            st[i] = *(const uint4*)(src + (size_t)row * K + sl * 8);
        }
    };
    auto dswrite = [&](uint4* st) {
#pragma unroll
        for (int i = 0; i < LOADS; ++i) {
            int ch = i * 1024 + tid;
            int row = ch >> 6, sl = ch & 63;
            *(uint4*)((char*)As + row * (K * 2) + ((sl ^ (row & 7)) * 16)) = st[i];
        }
    };

    const int chW = tid >> 2, pqW = tid & 3;
    const float gch = lng[chW], bch = lnb_[chW];

    uint4 st[LOADS];
    loadregs(t0, st);
    dswrite(st);
    asm volatile("s_waitcnt lgkmcnt(0)" ::: "memory");
    __builtin_amdgcn_sched_barrier(0);
    __builtin_amdgcn_s_barrier();

    for (int t = t0; t < NT; t += G) {
        const bool hn = (t + G) < NT;
        if (hn) loadregs(t + G, st);

        f32x4 acc[2];
        acc[0] = (f32x4){0.f, 0.f, 0.f, 0.f};
        acc[1] = (f32x4){0.f, 0.f, 0.f, 0.f};

        __builtin_amdgcn_s_setprio(1);
#pragma unroll
        for (int ks = 0; ks < KS; ++ks) {
            short8 a[2];
#pragma unroll
            for (int rr = 0; rr < 2; ++rr) {
                int row = rr * 16 + rl15;
                int sw = (ks * 4 + kg) ^ (row & 7);
                a[rr] = *(const short8*)((const char*)As + row * (K * 2) + sw * 16);
            }
#pragma unroll
            for (int rr = 0; rr < 2; ++rr)
                acc[rr] = __builtin_amdgcn_mfma_f32_16x16x32_bf16(a[rr], wf[ks], acc[rr], 0, 0, 0);
        }
        __builtin_amdgcn_s_setprio(0);
        __builtin_amdgcn_s_barrier();
        if (hn) {
            dswrite(st);
            asm volatile("s_waitcnt lgkmcnt(0)" ::: "memory");
            __builtin_amdgcn_sched_barrier(0);
        }
        __builtin_amdgcn_s_barrier();

#pragma unroll
        for (int rr = 0; rr < 2; ++rr)
#pragma unroll
            for (int ri = 0; ri < 4; ++ri)
                lnb[rr * 16 + kg * 4 + ri][col] = acc[rr][ri];
        __syncthreads();

        {
            const int row = tid >> 5, cg = tid & 31;
            float s = 0.f, s2 = 0.f;
#pragma unroll
            for (int j = 0; j < 8; ++j) {
                float v = lnb[row][cg + j * 32];
                s += v; s2 += v * v;
            }
#pragma unroll
            for (int o = 16; o > 0; o >>= 1) {
                s += __shfl_xor(s, o, 32);
                s2 += __shfl_xor(s2, o, 32);
            }
            if (cg == 0) {
                float mu = s * (1.f / 256.f);
                float var = s2 * (1.f / 256.f) - mu * mu;
                mu_s[row] = mu;
                rs_s[row] = rsqrtf(var + 1e-6f);
            }
        }
        __syncthreads();

        {
            const int pixBase = t * 32 + pqW * 8;
            if (pixBase + 8 <= HWSZ) {
                float o0[8];
#pragma unroll
                for (int j = 0; j < 8; ++j) {
                    const int pl = pqW * 8 + j;
                    o0[j] = (lnb[pl][chW] - mu_s[pl]) * rs_s[pl] * gch + bch;
                }
                float* op = out + (size_t)chW * HWSZ + pixBase;
                *(float4*)(op)     = make_float4(o0[0], o0[1], o0[2], o0[3]);
                *(float4*)(op + 4) = make_float4(o0[4], o0[5], o0[6], o0[7]);
            } else {
                for (int j = 0; j < 8; ++j) {
                    const int pix = pixBase + j;
                    if (pix < HWSZ) {
                        const int pl = pqW * 8 + j;
                        out[(size_t)chW * HWSZ + pix] =
                            (lnb[pl][chW] - mu_s[pl]) * rs_s[pl] * gch + bch;
                    }
                }
            }
        }
        __syncthreads();
    }
}

// ---------------------------------------------------------------------------
// Per-chunk prep.
// ---------------------------------------------------------------------------
__launch_bounds__(256)
__global__ void prep_k(const float* __restrict__ tail, const float* __restrict__ db0,
                       const float* __restrict__ db1, const float* __restrict__ al0,
                       const float* __restrict__ al1, const int* __restrict__ mor0,
                       const int* __restrict__ mor1, float* __restrict__ dtb,
                       float* __restrict__ acsb, float* __restrict__ csum)
{
    const int z = blockIdx.y;
    const float* dt_bias = z ? db1 : db0;
    const float* A_log = z ? al1 : al0;
    const int* mor = z ? mor1 : mor0;
    const float* tl = tail + (size_t)z * L_SEQ * 12;
    float* dtbp = dtb + (size_t)z * L_SEQ * 4;
    float* acsp = acsb + (size_t)z * L_SEQ * 4;
    float* csp = csum + (size_t)z * NCH * 4;

    const int c = blockIdx.x;
    const int l = threadIdx.x;
    const int lane = l & 63, w = l >> 6;
    const int gl = c * 256 + l;
    const bool valid = gl < L_SEQ;
    float v[NH] = {0.f, 0.f, 0.f, 0.f};
    if (valid) {
        const int pos = mor[gl];
        float4 dv = *(const float4*)(tl + (size_t)pos * 12 + 8);
        const float* dp = (const float*)&dv;
#pragma unroll
        for (int h = 0; h < NH; ++h) {
            float dt = softplus_f(dp[h] + dt_bias[h]);
            dtbp[(size_t)gl * 4 + h] = dt;
            v[h] = -__expf(A_log[h]) * LOG2E * dt;
        }
    }
#pragma unroll
    for (int off = 1; off < 64; off <<= 1) {
#pragma unroll
        for (int h = 0; h < NH; ++h) {
            float tt = __shfl_up(v[h], off, 64);
            if (lane >= off) v[h] += tt;
        }
    }
    __shared__ float wsum[4][NH];
    if (lane == 63)
#pragma unroll
        for (int h = 0; h < NH; ++h) wsum[w][h] = v[h];
    __syncthreads();
#pragma unroll
    for (int h = 0; h < NH; ++h) {
        float o = 0.f;
#pragma unroll
        for (int w2 = 0; w2 < 4; ++w2) if (w2 < w) o += wsum[w2][h];
        v[h] += o;
    }
    if (valid)
#pragma unroll
        for (int h = 0; h < NH; ++h) acsp[(size_t)gl * 4 + h] = v[h];
    if (l == 255)
#pragma unroll
        for (int h = 0; h < NH; ++h) csp[c * 4 + h] = v[h];
}

// ---------------------------------------------------------------------------
// Chunk-end states, partial.
// ---------------------------------------------------------------------------
__launch_bounds__(256)
__global__ void states_part_k(const u16* __restrict__ zxb, const float* __restrict__ dtb,
                              const float* __restrict__ tail, const float* __restrict__ acsb,
                              const float* __restrict__ csum, const int* __restrict__ mor0,
                              const int* __restrict__ mor1, float* __restrict__ spart)
{
    const int z = blockIdx.z;
    const u16* zxp = zxb + (size_t)z * L_SEQ * 512;
    const float* dtbp = dtb + (size_t)z * L_SEQ * 4;
    const float* tl = tail + (size_t)z * L_SEQ * 12;
    const float* acsp = acsb + (size_t)z * L_SEQ * 4;
    const float* csp = csum + (size_t)z * NCH * 4;
    const int* mor = z ? mor1 : mor0;
    float* spp = spart + (size_t)z * NCH * 4096;

    __shared__ float coef[64][16];
    __shared__ int posL[64];
    const int c = blockIdx.x, q = blockIdx.y;
    const int tid = threadIdx.x;
    {
        const int l_loc = tid >> 2, h = tid & 3;
        const int gl = c * 256 + q * 64 + l_loc;
        const int pos = (gl < L_SEQ) ? mor[gl] : 0;
        float4 Bv = make_float4(0.f, 0.f, 0.f, 0.f);
        float e = 0.f;
        if (gl < L_SEQ) {
            Bv = *(const float4*)(tl + (size_t)pos * 12);
            e = exp2f(csp[c * 4 + h] - acsp[(size_t)gl * 4 + h]) * dtbp[(size_t)gl * 4 + h];
        }
        *(float4*)&coef[l_loc][h * 4] = make_float4(Bv.x * e, Bv.y * e, Bv.z * e, Bv.w * e);
        if (h == 0) posL[l_loc] = pos;
    }
    __syncthreads();
    const int h = tid >> 6;
    f32x4 acc = (f32x4){0.f, 0.f, 0.f, 0.f};
#pragma unroll 4
    for (int j = 0; j < 64; ++j) {
        const int gl = c * 256 + q * 64 + j;
        float xs = 0.f;
        if (gl < L_SEQ) xs = bf2f(zxp[(size_t)posL[j] * 512 + 256 + tid]);
        float4 cf = *(const float4*)&coef[j][h * 4];
        acc[0] += cf.x * xs; acc[1] += cf.y * xs;
        acc[2] += cf.z * xs; acc[3] += cf.w * xs;
    }
    *(f32x4*)(spp + ((size_t)(c * 4 + q) * 256 + tid) * 4) = acc;
}

// ---------------------------------------------------------------------------
// Inter-chunk scan with fused q-reduction.
// ---------------------------------------------------------------------------
__launch_bounds__(256)
__global__ void chunkscan_k(const float* __restrict__ csum, const float* __restrict__ spart,
                            float* __restrict__ prev)
{
    const int z = blockIdx.y;
    const float* csp = csum + (size_t)z * NCH * 4;
    const float* spp = spart + (size_t)z * NCH * 4096;
    float* prp = prev + (size_t)z * NCH * 1024;

    const int h = blockIdx.x;
    const int tid = threadIdx.x;
    __shared__ float ecs[NCH];
    if (tid < NCH) ecs[tid] = exp2f(csp[tid * 4 + h]);
    __syncthreads();
    float run = 0.f;
#pragma unroll 2
    for (int c = 0; c < NCH; ++c) {
        const float* sp = spp + (size_t)(c * 4) * 1024 + h * 256 + tid;
        float s = sp[0] + sp[1024] + sp[2048] + sp[3072];
        prp[(size_t)c * 1024 + h * 256 + tid] = run;
        run = run * ecs[c] + s;
    }
}

// ---------------------------------------------------------------------------
// MFMA per-chunk output v4.1 (exp-factored).
// ---------------------------------------------------------------------------
__launch_bounds__(1024, 4)
__global__ void ychunk4_k(const u16* __restrict__ zxb, const float* __restrict__ tail,
                          const float* __restrict__ dtb, const float* __restrict__ acsb,
                          const float* __restrict__ prev, const float* __restrict__ Dv0,
                          const float* __restrict__ Dv1, const int* __restrict__ mor0,
                          const int* __restrict__ mor1, u16* __restrict__ cat)
{
    const int z = blockIdx.z;
    const u16* zxp = zxb + (size_t)z * L_SEQ * 512;
    const float* tl = tail + (size_t)z * L_SEQ * 12;
    const float* dtbp = dtb + (size_t)z * L_SEQ * 4;
    const float* acsp = acsb + (size_t)z * L_SEQ * 4;
    const float* prp = prev + (size_t)z * NCH * 1024;
    const float* Dv = z ? Dv1 : Dv0;
    const int* mor = z ? mor1 : mor0;
    const int catOff = z * 256;

    __shared__ __align__(16) u16 Xt[64 * 256];
    __shared__ __align__(16) u16 Xp[64 * 40];
    __shared__ float4 sBdt[256];
    __shared__ float4 sC[256];
    __shared__ float  sA2[256];
    __shared__ int    morL[256];

    const int c = blockIdx.x, h = blockIdx.y;
    const int tid = threadIdx.x;
    const int lane = tid & 63, w = tid >> 6;     // w = 0..15

    if (tid < 256) {
        const int s = tid, gl = c * 256 + s;
        const int pos = (gl < L_SEQ) ? mor[gl] : 0;
        morL[s] = pos;
        if (gl < L_SEQ) {
            const float* tr = tl + (size_t)pos * 12;
            float4 B4 = *(const float4*)tr;
            float4 C4v = *(const float4*)(tr + 4);
            float dt = dtbp[(size_t)gl * 4 + h];
            sBdt[s] = make_float4(B4.x * dt, B4.y * dt, B4.z * dt, B4.w * dt);
            sC[s] = C4v;
            sA2[s] = acsp[(size_t)gl * 4 + h];
        } else {
            sBdt[s] = make_float4(0.f, 0.f, 0.f, 0.f);
            sC[s] = make_float4(0.f, 0.f, 0.f, 0.f);
            sA2[s] = 0.f;
        }
    } else if (tid < 320) {
        int i = tid - 256;
        float4 pv = *(const float4*)(prp + (size_t)c * 1024 + h * 256 + i * 4);
        u32 w0 = cvtpk(pv.x, pv.y), w1 = cvtpk(pv.z, pv.w);
        uint4* row = (uint4*)((char*)Xp + i * 80);
        row[0] = make_uint4(w0, w1, 0u, 0u);
        row[1] = make_uint4(0u, 0u, 0u, 0u);
        row[2] = make_uint4(0u, 0u, 0u, 0u);
        row[3] = make_uint4(0u, 0u, 0u, 0u);
    }
    __syncthreads();

    if (tid < 256) {
        const int s = tid;
        float es = exp2f(sA2[s & ~7] - sA2[s]);
        float4 b4 = sBdt[s];
        sBdt[s] = make_float4(b4.x * es, b4.y * es, b4.z * es, b4.w * es);
    }
    {
        const int p = lane;
        const size_t colOff = 256 + h * 64 + p;
#pragma unroll
        for (int jq = 0; jq < 2; ++jq) {
            const int s0 = w * 16 + jq * 8;
            u32 wd[4];
#pragma unroll
            for (int q2 = 0; q2 < 4; ++q2) {
                int sIdx = s0 + q2 * 2;
                int gl0 = c * 256 + sIdx;
                u32 lo = (gl0     < L_SEQ) ? (u32)zxp[(size_t)morL[sIdx] * 512 + colOff] : 0u;
                u32 hi = (gl0 + 1 < L_SEQ) ? (u32)zxp[(size_t)morL[sIdx + 1] * 512 + colOff] : 0u;
                wd[q2] = lo | (hi << 16);
            }
            u32 off = (u32)(p * 512 + s0 * 2) ^ (u32)((p & 15) << 4);
            *(uint4*)((char*)Xt + off) = make_uint4(wd[0], wd[1], wd[2], wd[3]);
        }
    }
    __syncthreads();

    const int rl15 = lane & 15, kg = lane >> 4;
    const int R = w * 16;
    const int km = w >> 1;
    const float Dh = Dv[h];
    const int lrow = R + rl15;
    const float4 C4 = sC[lrow];
    const float al2 = sA2[lrow];

    f32x4 acc[4];
#pragma unroll
    for (int n = 0; n < 4; ++n) acc[n] = (f32x4){0.f, 0.f, 0.f, 0.f};

    for (int ks = 0; ks <= km; ++ks) {
        const int s0 = ks * 32 + kg * 8;
        short8 bf[4];
#pragma unroll
        for (int n = 0; n < 4; ++n) {
            int col = n * 16 + rl15;
            u32 off = (u32)(col * 512 + ks * 64 + kg * 16) ^ (u32)((col & 15) << 4);
            bf[n] = *(const short8*)((const char*)Xt + off);
        }
        const float eL = exp2f(al2 - sA2[s0]);
        float4 Bv[8];
#pragma unroll
        for (int j = 0; j < 8; ++j) Bv[j] = sBdt[s0 + j];
        float vv[8];
        if (ks < km) {
#pragma unroll
            for (int j = 0; j < 8; ++j) {
                float dot = C4.x * Bv[j].x + C4.y * Bv[j].y
                          + C4.z * Bv[j].z + C4.w * Bv[j].w;
                vv[j] = dot * eL;
            }
        } else {
#pragma unroll
            for (int j = 0; j < 8; ++j) {
                int s = s0 + j;
                float dot = C4.x * Bv[j].x + C4.y * Bv[j].y
                          + C4.z * Bv[j].z + C4.w * Bv[j].w;
                float v = dot * eL;
                v = (s <= lrow) ? v : 0.f;
                vv[j] = (s == lrow) ? v + Dh : v;
            }
        }
        union { u32 wd[4]; short8 v; } aw;
#pragma unroll
        for (int q2 = 0; q2 < 4; ++q2) aw.wd[q2] = cvtpk(vv[2 * q2], vv[2 * q2 + 1]);
#pragma unroll
        for (int n = 0; n < 4; ++n)
            acc[n] = __builtin_amdgcn_mfma_f32_16x16x32_bf16(aw.v, bf[n], acc[n], 0, 0, 0);
    }
    {
        short8 bp[4];
#pragma unroll
        for (int n = 0; n < 4; ++n) {
            int col = n * 16 + rl15;
            bp[n] = *(const short8*)((const char*)Xp + col * 80 + kg * 16);
        }
        float ea = exp2f(al2);
        union { u32 wd[4]; short8 v; } aw;
        aw.wd[0] = (kg == 0) ? cvtpk(ea * C4.x, ea * C4.y) : 0u;
        aw.wd[1] = (kg == 0) ? cvtpk(ea * C4.z, ea * C4.w) : 0u;
        aw.wd[2] = 0u; aw.wd[3] = 0u;
#pragma unroll
        for (int n = 0; n < 4; ++n)
            acc[n] = __builtin_amdgcn_mfma_f32_16x16x32_bf16(aw.v, bp[n], acc[n], 0, 0, 0);
    }

#pragma unroll
    for (int r = 0; r < 4; ++r) {
        const int row = R + kg * 4 + r;
        const int gl = c * 256 + row;
        if (gl >= L_SEQ) continue;
        const int pos = morL[row];
        const size_t zbase = (size_t)pos * 512 + h * 64;
        u16* orow = cat + (size_t)pos * 512 + catOff + h * 64;
#pragma unroll
        for (int n = 0; n < 4; ++n) {
            const int col = n * 16 + rl15;
            float zs = bf2f(zxp[zbase + col]);
            float y = acc[n][r] * zs;
            orow[col] = (u16)cvtpk(y, y);
        }
    }
}

// ---------------------------------------------------------------------------
extern "C" void kernel_launch(void* const* d_in, const int* in_sizes, int n_in,
                              void* d_out, int out_size, void* d_ws, size_t ws_size,
                              hipStream_t stream)
{
    const float* x      = (const float*)d_in[0];
    const float* W_in0  = (const float*)d_in[1];
    const float* W_in1  = (const float*)d_in[2];
    const float* dt_b0  = (const float*)d_in[3];
    const float* dt_b1  = (const float*)d_in[4];
    const float* A_log0 = (const float*)d_in[5];
    const float* A_log1 = (const float*)d_in[6];
    const float* Dv0    = (const float*)d_in[7];
    const float* Dv1    = (const float*)d_in[8];
    const float* W_out  = (const float*)d_in[9];
    const float* ln_g   = (const float*)d_in[10];
    const float* ln_b   = (const float*)d_in[11];
    const int*   mor0   = (const int*)d_in[12];
    const int*   mor1   = (const int*)d_in[13];

    char* ws = (char*)d_ws;
    size_t off = 0;
    auto alloc = [&](size_t bytes) { char* p = ws + off; off += (bytes + 255) & ~(size_t)255; return p; };
    u16*   xt    = (u16*)  alloc((size_t)MPAD * 256 * 2);
    u16*   zxb   = (u16*)  alloc((size_t)2 * L_SEQ * 512 * 2);
    u16*   cat   = (u16*)  alloc((size_t)MPAD * 512 * 2);
    float* tail  = (float*)alloc((size_t)2 * L_SEQ * 12 * 4);
    u16*   wbufI = (u16*)  alloc((size_t)1280 * 256 * 2);
    u16*   wbufO = (u16*)  alloc((size_t)256 * 512 * 2);
    float* dtb   = (float*)alloc((size_t)2 * L_SEQ * 4 * 4);
    float* acsb  = (float*)alloc((size_t)2 * L_SEQ * 4 * 4);
    float* csum  = (float*)alloc((size_t)2 * NCH * 4 * 4);
    float* spart = (float*)alloc((size_t)2 * NCH * 4096 * 4);
    float* prev  = (float*)alloc((size_t)2 * NCH * 1024 * 4);

    convpad2_k<<<dim3(640, 2), 256, 0, stream>>>(W_in0, W_in1, wbufI, 524, 256, (size_t)640 * 256);
    convpad2_k<<<dim3(256, 1), 256, 0, stream>>>(W_out, W_out, wbufO, 256, 512, 0);
    xpose_k<<<507, 256, 0, stream>>>(x, xt);
    zero2_k<<<dim3(112, 1), 256, 0, stream>>>(xt + (size_t)L_SEQ * 256, 0, 112 * 256);

    // merged in-proj: M=32512, N=1280, K=256 — DEPTH-2, NFRAG=1, 10 panels
    inproj_k<<<1020, 512, 0, stream>>>(xt, wbufI, zxb, tail);

    prep_k<<<dim3(NCH, 2), 256, 0, stream>>>(tail, dt_b0, dt_b1, A_log0, A_log1,
                                             mor0, mor1, dtb, acsb, csum);
    states_part_k<<<dim3(NCH, 4, 2), 256, 0, stream>>>(zxb, dtb, tail, acsb, csum,
                                                       mor0, mor1, spart);
    chunkscan_k<<<dim3(4, 2), 256, 0, stream>>>(csum, spart, prev);
    ychunk4_k<<<dim3(NCH, NH, 2), 1024, 0, stream>>>(zxb, tail, dtb, acsb, prev,
                                                     Dv0, Dv1, mor0, mor1, cat);

    zero2_k<<<dim3(224, 1), 256, 0, stream>>>(cat + (size_t)L_SEQ * 512, 0, 112 * 512);
    // out-proj + fused LayerNorm + transpose: M=32512, N=256, K=512
    wsgemmLN_k<508><<<508, 1024, 0, stream>>>(cat, wbufO, ln_g, ln_b, (float*)d_out);
}

// Round 23
// 257.590 us; speedup vs baseline: 1.0229x; 1.0229x over previous
//
#include <hip/hip_runtime.h>
#include <cstdint>

#define L_SEQ 32400
#define HWSZ  32400
#define MPAD  32512
#define NCH   127
#define NH    4
#define LOG2E 1.4426950408889634f

typedef unsigned short u16;
typedef unsigned int   u32;
typedef __attribute__((ext_vector_type(8))) short short8;
typedef __attribute__((ext_vector_type(4))) float f32x4;

__device__ __forceinline__ float silu_f(float v) {
    float e = __expf(-v);
    return v * __builtin_amdgcn_rcpf(1.f + e);
}
__device__ __forceinline__ float softplus_f(float v) { return v > 20.f ? v : log1pf(__expf(v)); }
__device__ __forceinline__ u16 f2bf(float f) {
    u32 u = __float_as_uint(f);
    u += 0x7FFFu + ((u >> 16) & 1u);
    return (u16)(u >> 16);
}
__device__ __forceinline__ u32 cvtpk(float lo, float hi) {
    u32 r;
    asm("v_cvt_pk_bf16_f32 %0, %1, %2" : "=v"(r) : "v"(lo), "v"(hi));
    return r;
}
__device__ __forceinline__ float bf2f(u32 u) { return __uint_as_float(u << 16); }

// ---------------------------------------------------------------------------
// Transpose x [C][HW] -> xt [pix][C] bf16.
// ---------------------------------------------------------------------------
__launch_bounds__(256)
__global__ void xpose_k(const float* __restrict__ x, u16* __restrict__ xt)
{
    __shared__ u16 tile[256][66];
    const int pix0 = blockIdx.x * 64;
    const int tid = threadIdx.x;
    const int pl = tid & 63, cq = tid >> 6;
    const int pix = pix0 + pl;
    const bool pv = pix < HWSZ;
#pragma unroll 4
    for (int j = 0; j < 64; ++j) {
        int c = cq * 64 + j;
        float v = pv ? x[(size_t)c * HWSZ + pix] : 0.f;
        tile[c][pl] = f2bf(v);
    }
    __syncthreads();
    for (int i = 0; i < 64; ++i) {
        int p2 = pix0 + i;
        if (p2 < HWSZ) xt[(size_t)p2 * 256 + tid] = tile[tid][i];
    }
}

__global__ void zero2_k(u16* __restrict__ p, size_t zstride, int n)
{
    int i = blockIdx.x * 256 + threadIdx.x;
    if (i < n) p[(size_t)blockIdx.y * zstride + i] = 0;
}

__global__ void convpad2_k(const float* __restrict__ s0, const float* __restrict__ s1,
                           u16* __restrict__ dst, int rows, int cols, size_t zstride)
{
    const int z = blockIdx.y;
    const float* __restrict__ src = z ? s1 : s0;
    u16* __restrict__ d = dst + (size_t)z * zstride;
    int r = blockIdx.x;
    for (int c = threadIdx.x; c < cols; c += 256)
        d[(size_t)r * cols + c] = (r < rows) ? f2bf(src[(size_t)r * cols + c]) : (u16)0;
}

// ---------------------------------------------------------------------------
// W-stationary streaming GEMM v2 (TM=32, launch_bounds(512,4) — the proven
// configuration from the 245.6us anchor).
// ---------------------------------------------------------------------------
template<int MODE, int K, int NFRAG, int NPANEL, int G>
__launch_bounds__(512, 4)
__global__ void wsgemm_k(const u16* __restrict__ A, const u16* __restrict__ W,
                         u16* __restrict__ outB, u16* __restrict__ zxb,
                         float* __restrict__ tail)
{
    constexpr int KS = K / 32;
    constexpr int SLOTS = K / 8;
    constexpr int LOADS = (32 * SLOTS) / 512;
    __shared__ u16 As[32 * K];

    const int nwg = NPANEL * G;
    const int orig = blockIdx.x;
    const int xcd = orig & 7;
    const int q = nwg >> 3, r = nwg & 7;
    const int wgid = (xcd < r ? xcd * (q + 1) : r * (q + 1) + (xcd - r) * q) + (orig >> 3);
    const int panel = wgid % NPANEL;
    const int t0 = wgid / NPANEL;

    const int tid = threadIdx.x;
    const int lane = tid & 63, wn = tid >> 6;
    const int rl15 = lane & 15, kg = lane >> 4;
    const int c0 = panel * (NFRAG * 128);
    const int NT = MPAD / 32;

    short8 wf[NFRAG][KS];
#pragma unroll
    for (int f = 0; f < NFRAG; ++f) {
        const int row = c0 + (wn * NFRAG + f) * 16 + rl15;
#pragma unroll
        for (int ks = 0; ks < KS; ++ks)
            wf[f][ks] = *(const short8*)(W + (size_t)row * K + ks * 32 + kg * 8);
    }

    auto loadregs = [&](int t, uint4* st) {
        const u16* src = A + (size_t)t * 32 * K;
#pragma unroll
        for (int i = 0; i < LOADS; ++i) {
            int ch = i * 512 + tid;
            int row = ch / SLOTS, sl = ch % SLOTS;
            st[i] = *(const uint4*)(src + (size_t)row * K + sl * 8);
        }
    };
    auto dswrite = [&](uint4* st) {
#pragma unroll
        for (int i = 0; i < LOADS; ++i) {
            int ch = i * 512 + tid;
            int row = ch / SLOTS, sl = ch % SLOTS;
            *(uint4*)((char*)As + row * (K * 2) + ((sl ^ (row & 7)) * 16)) = st[i];
        }
    };

    uint4 st[LOADS];
    loadregs(t0, st);
    dswrite(st);
    asm volatile("s_waitcnt lgkmcnt(0)" ::: "memory");
    __builtin_amdgcn_sched_barrier(0);
    __builtin_amdgcn_s_barrier();

    for (int t = t0; t < NT; t += G) {
        const bool hn = (t + G) < NT;
        if (hn) loadregs(t + G, st);

        f32x4 acc[2][NFRAG];
#pragma unroll
        for (int rr = 0; rr < 2; ++rr)
#pragma unroll
            for (int f = 0; f < NFRAG; ++f)
                acc[rr][f] = (f32x4){0.f, 0.f, 0.f, 0.f};

        __builtin_amdgcn_s_setprio(1);
#pragma unroll
        for (int ks = 0; ks < KS; ++ks) {
            short8 a[2];
#pragma unroll
            for (int rr = 0; rr < 2; ++rr) {
                int row = rr * 16 + rl15;
                int sw = (ks * 4 + kg) ^ (row & 7);
                a[rr] = *(const short8*)((const char*)As + row * (K * 2) + sw * 16);
            }
#pragma unroll
            for (int rr = 0; rr < 2; ++rr)
#pragma unroll
                for (int f = 0; f < NFRAG; ++f)
                    acc[rr][f] = __builtin_amdgcn_mfma_f32_16x16x32_bf16(a[rr], wf[f][ks], acc[rr][f], 0, 0, 0);
        }
        __builtin_amdgcn_s_setprio(0);
        __builtin_amdgcn_s_barrier();
        if (hn) {
            dswrite(st);
            asm volatile("s_waitcnt lgkmcnt(0)" ::: "memory");
            __builtin_amdgcn_sched_barrier(0);
        }
        __builtin_amdgcn_s_barrier();

#pragma unroll
        for (int rr = 0; rr < 2; ++rr) {
#pragma unroll
            for (int f = 0; f < NFRAG; ++f) {
                const int col = c0 + (wn * NFRAG + f) * 16 + rl15;
#pragma unroll
                for (int ri = 0; ri < 4; ++ri) {
                    const int gl = t * 32 + rr * 16 + kg * 4 + ri;
                    if (gl >= L_SEQ) continue;
                    float v = acc[rr][f][ri];
                    if (MODE == 0) {
                        outB[(size_t)gl * 256 + col] = (u16)cvtpk(v, v);
                    } else {
                        int zp = (col >= 640) ? 1 : 0;
                        int c6 = col - zp * 640;
                        if (c6 < 512) {
                            float s = silu_f(v);
                            zxb[(size_t)zp * L_SEQ * 512 + (size_t)gl * 512 + c6] = (u16)cvtpk(s, s);
                        } else if (c6 < 520) {
                            tail[(size_t)zp * L_SEQ * 12 + (size_t)gl * 12 + (c6 - 512)] = silu_f(v);
                        } else if (c6 < 524) {
                            tail[(size_t)zp * L_SEQ * 12 + (size_t)gl * 12 + (c6 - 512)] = v;
                        }
                    }
                }
            }
        }
    }
}

// ---------------------------------------------------------------------------
// Out-proj GEMM with FUSED LayerNorm + transpose epilogue.
// ---------------------------------------------------------------------------
template<int G>
__launch_bounds__(1024, 2)
__global__ void wsgemmLN_k(const u16* __restrict__ A, const u16* __restrict__ W,
                           const float* __restrict__ lng, const float* __restrict__ lnb_,
                           float* __restrict__ out)
{
    constexpr int K = 512;
    constexpr int KS = K / 32;
    constexpr int SLOTS = K / 8;
    constexpr int LOADS = (32 * SLOTS) / 1024;
    __shared__ u16 As[32 * K];
    __shared__ float lnb[32][257];
    __shared__ float mu_s[32], rs_s[32];

    const int nwg = G;
    const int orig = blockIdx.x;
    const int xcd = orig & 7;
    const int q = nwg >> 3, r = nwg & 7;
    const int wgid = (xcd < r ? xcd * (q + 1) : r * (q + 1) + (xcd - r) * q) + (orig >> 3);
    const int t0 = wgid;

    const int tid = threadIdx.x;
    const int lane = tid & 63, wn = tid >> 6;
    const int rl15 = lane & 15, kg = lane >> 4;
    const int col = wn * 16 + rl15;
    const int NT = MPAD / 32;

    short8 wf[KS];
#pragma unroll
    for (int ks = 0; ks < KS; ++ks)
        wf[ks] = *(const short8*)(W + (size_t)col * K + ks * 32 + kg * 8);

    auto loadregs = [&](int t, uint4* st) {
        const u16* src = A + (size_t)t * 32 * K;
#pragma unroll
        for (int i = 0; i < LOADS; ++i) {
            int ch = i * 1024 + tid;
            int row = ch >> 6, sl = ch & 63;
            st[i] = *(const uint4*)(src + (size_t)row * K + sl * 8);
        }
    };
    auto dswrite = [&](uint4* st) {
#pragma unroll
        for (int i = 0; i < LOADS; ++i) {
            int ch = i * 1024 + tid;
            int row = ch >> 6, sl = ch & 63;
            *(uint4*)((char*)As + row * (K * 2) + ((sl ^ (row & 7)) * 16)) = st[i];
        }
    };

    const int chW = tid >> 2, pqW = tid & 3;
    const float gch = lng[chW], bch = lnb_[chW];

    uint4 st[LOADS];
    loadregs(t0, st);
    dswrite(st);
    asm volatile("s_waitcnt lgkmcnt(0)" ::: "memory");
    __builtin_amdgcn_sched_barrier(0);
    __builtin_amdgcn_s_barrier();

    for (int t = t0; t < NT; t += G) {
        const bool hn = (t + G) < NT;
        if (hn) loadregs(t + G, st);

        f32x4 acc[2];
        acc[0] = (f32x4){0.f, 0.f, 0.f, 0.f};
        acc[1] = (f32x4){0.f, 0.f, 0.f, 0.f};

        __builtin_amdgcn_s_setprio(1);
#pragma unroll
        for (int ks = 0; ks < KS; ++ks) {
            short8 a[2];
#pragma unroll
            for (int rr = 0; rr < 2; ++rr) {
                int row = rr * 16 + rl15;
                int sw = (ks * 4 + kg) ^ (row & 7);
                a[rr] = *(const short8*)((const char*)As + row * (K * 2) + sw * 16);
            }
#pragma unroll
            for (int rr = 0; rr < 2; ++rr)
                acc[rr] = __builtin_amdgcn_mfma_f32_16x16x32_bf16(a[rr], wf[ks], acc[rr], 0, 0, 0);
        }
        __builtin_amdgcn_s_setprio(0);
        __builtin_amdgcn_s_barrier();
        if (hn) {
            dswrite(st);
            asm volatile("s_waitcnt lgkmcnt(0)" ::: "memory");
            __builtin_amdgcn_sched_barrier(0);
        }
        __builtin_amdgcn_s_barrier();

#pragma unroll
        for (int rr = 0; rr < 2; ++rr)
#pragma unroll
            for (int ri = 0; ri < 4; ++ri)
                lnb[rr * 16 + kg * 4 + ri][col] = acc[rr][ri];
        __syncthreads();

        {
            const int row = tid >> 5, cg = tid & 31;
            float s = 0.f, s2 = 0.f;
#pragma unroll
            for (int j = 0; j < 8; ++j) {
                float v = lnb[row][cg + j * 32];
                s += v; s2 += v * v;
            }
#pragma unroll
            for (int o = 16; o > 0; o >>= 1) {
                s += __shfl_xor(s, o, 32);
                s2 += __shfl_xor(s2, o, 32);
            }
            if (cg == 0) {
                float mu = s * (1.f / 256.f);
                float var = s2 * (1.f / 256.f) - mu * mu;
                mu_s[row] = mu;
                rs_s[row] = rsqrtf(var + 1e-6f);
            }
        }
        __syncthreads();

        {
            const int pixBase = t * 32 + pqW * 8;
            if (pixBase + 8 <= HWSZ) {
                float o0[8];
#pragma unroll
                for (int j = 0; j < 8; ++j) {
                    const int pl = pqW * 8 + j;
                    o0[j] = (lnb[pl][chW] - mu_s[pl]) * rs_s[pl] * gch + bch;
                }
                float* op = out + (size_t)chW * HWSZ + pixBase;
                *(float4*)(op)     = make_float4(o0[0], o0[1], o0[2], o0[3]);
                *(float4*)(op + 4) = make_float4(o0[4], o0[5], o0[6], o0[7]);
            } else {
                for (int j = 0; j < 8; ++j) {
                    const int pix = pixBase + j;
                    if (pix < HWSZ) {
                        const int pl = pqW * 8 + j;
                        out[(size_t)chW * HWSZ + pix] =
                            (lnb[pl][chW] - mu_s[pl]) * rs_s[pl] * gch + bch;
                    }
                }
            }
        }
        __syncthreads();
    }
}

// ---------------------------------------------------------------------------
// Per-chunk prep.
// ---------------------------------------------------------------------------
__launch_bounds__(256)
__global__ void prep_k(const float* __restrict__ tail, const float* __restrict__ db0,
                       const float* __restrict__ db1, const float* __restrict__ al0,
                       const float* __restrict__ al1, const int* __restrict__ mor0,
                       const int* __restrict__ mor1, float* __restrict__ dtb,
                       float* __restrict__ acsb, float* __restrict__ csum)
{
    const int z = blockIdx.y;
    const float* dt_bias = z ? db1 : db0;
    const float* A_log = z ? al1 : al0;
    const int* mor = z ? mor1 : mor0;
    const float* tl = tail + (size_t)z * L_SEQ * 12;
    float* dtbp = dtb + (size_t)z * L_SEQ * 4;
    float* acsp = acsb + (size_t)z * L_SEQ * 4;
    float* csp = csum + (size_t)z * NCH * 4;

    const int c = blockIdx.x;
    const int l = threadIdx.x;
    const int lane = l & 63, w = l >> 6;
    const int gl = c * 256 + l;
    const bool valid = gl < L_SEQ;
    float v[NH] = {0.f, 0.f, 0.f, 0.f};
    if (valid) {
        const int pos = mor[gl];
        float4 dv = *(const float4*)(tl + (size_t)pos * 12 + 8);
        const float* dp = (const float*)&dv;
#pragma unroll
        for (int h = 0; h < NH; ++h) {
            float dt = softplus_f(dp[h] + dt_bias[h]);
            dtbp[(size_t)gl * 4 + h] = dt;
            v[h] = -__expf(A_log[h]) * LOG2E * dt;
        }
    }
#pragma unroll
    for (int off = 1; off < 64; off <<= 1) {
#pragma unroll
        for (int h = 0; h < NH; ++h) {
            float tt = __shfl_up(v[h], off, 64);
            if (lane >= off) v[h] += tt;
        }
    }
    __shared__ float wsum[4][NH];
    if (lane == 63)
#pragma unroll
        for (int h = 0; h < NH; ++h) wsum[w][h] = v[h];
    __syncthreads();
#pragma unroll
    for (int h = 0; h < NH; ++h) {
        float o = 0.f;
#pragma unroll
        for (int w2 = 0; w2 < 4; ++w2) if (w2 < w) o += wsum[w2][h];
        v[h] += o;
    }
    if (valid)
#pragma unroll
        for (int h = 0; h < NH; ++h) acsp[(size_t)gl * 4 + h] = v[h];
    if (l == 255)
#pragma unroll
        for (int h = 0; h < NH; ++h) csp[c * 4 + h] = v[h];
}

// ---------------------------------------------------------------------------
// Chunk-end states, partial.
// ---------------------------------------------------------------------------
__launch_bounds__(256)
__global__ void states_part_k(const u16* __restrict__ zxb, const float* __restrict__ dtb,
                              const float* __restrict__ tail, const float* __restrict__ acsb,
                              const float* __restrict__ csum, const int* __restrict__ mor0,
                              const int* __restrict__ mor1, float* __restrict__ spart)
{
    const int z = blockIdx.z;
    const u16* zxp = zxb + (size_t)z * L_SEQ * 512;
    const float* dtbp = dtb + (size_t)z * L_SEQ * 4;
    const float* tl = tail + (size_t)z * L_SEQ * 12;
    const float* acsp = acsb + (size_t)z * L_SEQ * 4;
    const float* csp = csum + (size_t)z * NCH * 4;
    const int* mor = z ? mor1 : mor0;
    float* spp = spart + (size_t)z * NCH * 4096;

    __shared__ float coef[64][16];
    __shared__ int posL[64];
    const int c = blockIdx.x, q = blockIdx.y;
    const int tid = threadIdx.x;
    {
        const int l_loc = tid >> 2, h = tid & 3;
        const int gl = c * 256 + q * 64 + l_loc;
        const int pos = (gl < L_SEQ) ? mor[gl] : 0;
        float4 Bv = make_float4(0.f, 0.f, 0.f, 0.f);
        float e = 0.f;
        if (gl < L_SEQ) {
            Bv = *(const float4*)(tl + (size_t)pos * 12);
            e = exp2f(csp[c * 4 + h] - acsp[(size_t)gl * 4 + h]) * dtbp[(size_t)gl * 4 + h];
        }
        *(float4*)&coef[l_loc][h * 4] = make_float4(Bv.x * e, Bv.y * e, Bv.z * e, Bv.w * e);
        if (h == 0) posL[l_loc] = pos;
    }
    __syncthreads();
    const int h = tid >> 6;
    f32x4 acc = (f32x4){0.f, 0.f, 0.f, 0.f};
#pragma unroll 4
    for (int j = 0; j < 64; ++j) {
        const int gl = c * 256 + q * 64 + j;
        float xs = 0.f;
        if (gl < L_SEQ) xs = bf2f(zxp[(size_t)posL[j] * 512 + 256 + tid]);
        float4 cf = *(const float4*)&coef[j][h * 4];
        acc[0] += cf.x * xs; acc[1] += cf.y * xs;
        acc[2] += cf.z * xs; acc[3] += cf.w * xs;
    }
    *(f32x4*)(spp + ((size_t)(c * 4 + q) * 256 + tid) * 4) = acc;
}

// ---------------------------------------------------------------------------
// Inter-chunk scan with fused q-reduction.
// ---------------------------------------------------------------------------
__launch_bounds__(256)
__global__ void chunkscan_k(const float* __restrict__ csum, const float* __restrict__ spart,
                            float* __restrict__ prev)
{
    const int z = blockIdx.y;
    const float* csp = csum + (size_t)z * NCH * 4;
    const float* spp = spart + (size_t)z * NCH * 4096;
    float* prp = prev + (size_t)z * NCH * 1024;

    const int h = blockIdx.x;
    const int tid = threadIdx.x;
    __shared__ float ecs[NCH];
    if (tid < NCH) ecs[tid] = exp2f(csp[tid * 4 + h]);
    __syncthreads();
    float run = 0.f;
#pragma unroll 2
    for (int c = 0; c < NCH; ++c) {
        const float* sp = spp + (size_t)(c * 4) * 1024 + h * 256 + tid;
        float s = sp[0] + sp[1024] + sp[2048] + sp[3072];
        prp[(size_t)c * 1024 + h * 256 + tid] = run;
        run = run * ecs[c] + s;
    }
}

// ---------------------------------------------------------------------------
// MFMA per-chunk output v4.1 (exp-factored).
// ---------------------------------------------------------------------------
__launch_bounds__(1024, 4)
__global__ void ychunk4_k(const u16* __restrict__ zxb, const float* __restrict__ tail,
                          const float* __restrict__ dtb, const float* __restrict__ acsb,
                          const float* __restrict__ prev, const float* __restrict__ Dv0,
                          const float* __restrict__ Dv1, const int* __restrict__ mor0,
                          const int* __restrict__ mor1, u16* __restrict__ cat)
{
    const int z = blockIdx.z;
    const u16* zxp = zxb + (size_t)z * L_SEQ * 512;
    const float* tl = tail + (size_t)z * L_SEQ * 12;
    const float* dtbp = dtb + (size_t)z * L_SEQ * 4;
    const float* acsp = acsb + (size_t)z * L_SEQ * 4;
    const float* prp = prev + (size_t)z * NCH * 1024;
    const float* Dv = z ? Dv1 : Dv0;
    const int* mor = z ? mor1 : mor0;
    const int catOff = z * 256;

    __shared__ __align__(16) u16 Xt[64 * 256];
    __shared__ __align__(16) u16 Xp[64 * 40];
    __shared__ float4 sBdt[256];
    __shared__ float4 sC[256];
    __shared__ float  sA2[256];
    __shared__ int    morL[256];

    const int c = blockIdx.x, h = blockIdx.y;
    const int tid = threadIdx.x;
    const int lane = tid & 63, w = tid >> 6;     // w = 0..15

    if (tid < 256) {
        const int s = tid, gl = c * 256 + s;
        const int pos = (gl < L_SEQ) ? mor[gl] : 0;
        morL[s] = pos;
        if (gl < L_SEQ) {
            const float* tr = tl + (size_t)pos * 12;
            float4 B4 = *(const float4*)tr;
            float4 C4v = *(const float4*)(tr + 4);
            float dt = dtbp[(size_t)gl * 4 + h];
            sBdt[s] = make_float4(B4.x * dt, B4.y * dt, B4.z * dt, B4.w * dt);
            sC[s] = C4v;
            sA2[s] = acsp[(size_t)gl * 4 + h];
        } else {
            sBdt[s] = make_float4(0.f, 0.f, 0.f, 0.f);
            sC[s] = make_float4(0.f, 0.f, 0.f, 0.f);
            sA2[s] = 0.f;
        }
    } else if (tid < 320) {
        int i = tid - 256;
        float4 pv = *(const float4*)(prp + (size_t)c * 1024 + h * 256 + i * 4);
        u32 w0 = cvtpk(pv.x, pv.y), w1 = cvtpk(pv.z, pv.w);
        uint4* row = (uint4*)((char*)Xp + i * 80);
        row[0] = make_uint4(w0, w1, 0u, 0u);
        row[1] = make_uint4(0u, 0u, 0u, 0u);
        row[2] = make_uint4(0u, 0u, 0u, 0u);
        row[3] = make_uint4(0u, 0u, 0u, 0u);
    }
    __syncthreads();

    if (tid < 256) {
        const int s = tid;
        float es = exp2f(sA2[s & ~7] - sA2[s]);
        float4 b4 = sBdt[s];
        sBdt[s] = make_float4(b4.x * es, b4.y * es, b4.z * es, b4.w * es);
    }
    {
        const int p = lane;
        const size_t colOff = 256 + h * 64 + p;
#pragma unroll
        for (int jq = 0; jq < 2; ++jq) {
            const int s0 = w * 16 + jq * 8;
            u32 wd[4];
#pragma unroll
            for (int q2 = 0; q2 < 4; ++q2) {
                int sIdx = s0 + q2 * 2;
                int gl0 = c * 256 + sIdx;
                u32 lo = (gl0     < L_SEQ) ? (u32)zxp[(size_t)morL[sIdx] * 512 + colOff] : 0u;
                u32 hi = (gl0 + 1 < L_SEQ) ? (u32)zxp[(size_t)morL[sIdx + 1] * 512 + colOff] : 0u;
                wd[q2] = lo | (hi << 16);
            }
            u32 off = (u32)(p * 512 + s0 * 2) ^ (u32)((p & 15) << 4);
            *(uint4*)((char*)Xt + off) = make_uint4(wd[0], wd[1], wd[2], wd[3]);
        }
    }
    __syncthreads();

    const int rl15 = lane & 15, kg = lane >> 4;
    const int R = w * 16;
    const int km = w >> 1;
    const float Dh = Dv[h];
    const int lrow = R + rl15;
    const float4 C4 = sC[lrow];
    const float al2 = sA2[lrow];

    f32x4 acc[4];
#pragma unroll
    for (int n = 0; n < 4; ++n) acc[n] = (f32x4){0.f, 0.f, 0.f, 0.f};

    for (int ks = 0; ks <= km; ++ks) {
        const int s0 = ks * 32 + kg * 8;
        short8 bf[4];
#pragma unroll
        for (int n = 0; n < 4; ++n) {
            int col = n * 16 + rl15;
            u32 off = (u32)(col * 512 + ks * 64 + kg * 16) ^ (u32)((col & 15) << 4);
            bf[n] = *(const short8*)((const char*)Xt + off);
        }
        const float eL = exp2f(al2 - sA2[s0]);
        float4 Bv[8];
#pragma unroll
        for (int j = 0; j < 8; ++j) Bv[j] = sBdt[s0 + j];
        float vv[8];
        if (ks < km) {
#pragma unroll
            for (int j = 0; j < 8; ++j) {
                float dot = C4.x * Bv[j].x + C4.y * Bv[j].y
                          + C4.z * Bv[j].z + C4.w * Bv[j].w;
                vv[j] = dot * eL;
            }
        } else {
#pragma unroll
            for (int j = 0; j < 8; ++j) {
                int s = s0 + j;
                float dot = C4.x * Bv[j].x + C4.y * Bv[j].y
                          + C4.z * Bv[j].z + C4.w * Bv[j].w;
                float v = dot * eL;
                v = (s <= lrow) ? v : 0.f;
                vv[j] = (s == lrow) ? v + Dh : v;
            }
        }
        union { u32 wd[4]; short8 v; } aw;
#pragma unroll
        for (int q2 = 0; q2 < 4; ++q2) aw.wd[q2] = cvtpk(vv[2 * q2], vv[2 * q2 + 1]);
#pragma unroll
        for (int n = 0; n < 4; ++n)
            acc[n] = __builtin_amdgcn_mfma_f32_16x16x32_bf16(aw.v, bf[n], acc[n], 0, 0, 0);
    }
    {
        short8 bp[4];
#pragma unroll
        for (int n = 0; n < 4; ++n) {
            int col = n * 16 + rl15;
            bp[n] = *(const short8*)((const char*)Xp + col * 80 + kg * 16);
        }
        float ea = exp2f(al2);
        union { u32 wd[4]; short8 v; } aw;
        aw.wd[0] = (kg == 0) ? cvtpk(ea * C4.x, ea * C4.y) : 0u;
        aw.wd[1] = (kg == 0) ? cvtpk(ea * C4.z, ea * C4.w) : 0u;
        aw.wd[2] = 0u; aw.wd[3] = 0u;
#pragma unroll
        for (int n = 0; n < 4; ++n)
            acc[n] = __builtin_amdgcn_mfma_f32_16x16x32_bf16(aw.v, bp[n], acc[n], 0, 0, 0);
    }

#pragma unroll
    for (int r = 0; r < 4; ++r) {
        const int row = R + kg * 4 + r;
        const int gl = c * 256 + row;
        if (gl >= L_SEQ) continue;
        const int pos = morL[row];
        const size_t zbase = (size_t)pos * 512 + h * 64;
        u16* orow = cat + (size_t)pos * 512 + catOff + h * 64;
#pragma unroll
        for (int n = 0; n < 4; ++n) {
            const int col = n * 16 + rl15;
            float zs = bf2f(zxp[zbase + col]);
            float y = acc[n][r] * zs;
            orow[col] = (u16)cvtpk(y, y);
        }
    }
}

// ---------------------------------------------------------------------------
extern "C" void kernel_launch(void* const* d_in, const int* in_sizes, int n_in,
                              void* d_out, int out_size, void* d_ws, size_t ws_size,
                              hipStream_t stream)
{
    const float* x      = (const float*)d_in[0];
    const float* W_in0  = (const float*)d_in[1];
    const float* W_in1  = (const float*)d_in[2];
    const float* dt_b0  = (const float*)d_in[3];
    const float* dt_b1  = (const float*)d_in[4];
    const float* A_log0 = (const float*)d_in[5];
    const float* A_log1 = (const float*)d_in[6];
    const float* Dv0    = (const float*)d_in[7];
    const float* Dv1    = (const float*)d_in[8];
    const float* W_out  = (const float*)d_in[9];
    const float* ln_g   = (const float*)d_in[10];
    const float* ln_b   = (const float*)d_in[11];
    const int*   mor0   = (const int*)d_in[12];
    const int*   mor1   = (const int*)d_in[13];

    char* ws = (char*)d_ws;
    size_t off = 0;
    auto alloc = [&](size_t bytes) { char* p = ws + off; off += (bytes + 255) & ~(size_t)255; return p; };
    u16*   xt    = (u16*)  alloc((size_t)MPAD * 256 * 2);
    u16*   zxb   = (u16*)  alloc((size_t)2 * L_SEQ * 512 * 2);
    u16*   cat   = (u16*)  alloc((size_t)MPAD * 512 * 2);
    float* tail  = (float*)alloc((size_t)2 * L_SEQ * 12 * 4);
    u16*   wbufI = (u16*)  alloc((size_t)1280 * 256 * 2);
    u16*   wbufO = (u16*)  alloc((size_t)256 * 512 * 2);
    float* dtb   = (float*)alloc((size_t)2 * L_SEQ * 4 * 4);
    float* acsb  = (float*)alloc((size_t)2 * L_SEQ * 4 * 4);
    float* csum  = (float*)alloc((size_t)2 * NCH * 4 * 4);
    float* spart = (float*)alloc((size_t)2 * NCH * 4096 * 4);
    float* prev  = (float*)alloc((size_t)2 * NCH * 1024 * 4);

    convpad2_k<<<dim3(640, 2), 256, 0, stream>>>(W_in0, W_in1, wbufI, 524, 256, (size_t)640 * 256);
    convpad2_k<<<dim3(256, 1), 256, 0, stream>>>(W_out, W_out, wbufO, 256, 512, 0);
    xpose_k<<<507, 256, 0, stream>>>(x, xt);
    zero2_k<<<dim3(112, 1), 256, 0, stream>>>(xt + (size_t)L_SEQ * 256, 0, 112 * 256);

    // merged in-proj: M=32512, N=1280, K=256
    wsgemm_k<1, 256, 2, 5, 102><<<510, 512, 0, stream>>>(xt, wbufI, nullptr, zxb, tail);

    prep_k<<<dim3(NCH, 2), 256, 0, stream>>>(tail, dt_b0, dt_b1, A_log0, A_log1,
                                             mor0, mor1, dtb, acsb, csum);
    states_part_k<<<dim3(NCH, 4, 2), 256, 0, stream>>>(zxb, dtb, tail, acsb, csum,
                                                       mor0, mor1, spart);
    chunkscan_k<<<dim3(4, 2), 256, 0, stream>>>(csum, spart, prev);
    ychunk4_k<<<dim3(NCH, NH, 2), 1024, 0, stream>>>(zxb, tail, dtb, acsb, prev,
                                                     Dv0, Dv1, mor0, mor1, cat);

    zero2_k<<<dim3(224, 1), 256, 0, stream>>>(cat + (size_t)L_SEQ * 512, 0, 112 * 512);
    // out-proj + fused LayerNorm + transpose: M=32512, N=256, K=512
    wsgemmLN_k<508><<<508, 1024, 0, stream>>>(cat, wbufO, ln_g, ln_b, (float*)d_out);
}

// Round 24
// 245.689 us; speedup vs baseline: 1.0724x; 1.0484x over previous
//
#include <hip/hip_runtime.h>
#include <cstdint>

#define L_SEQ 32400
#define HWSZ  32400
#define MPAD  32512
#define NCH   127
#define NH    4
#define LOG2E 1.4426950408889634f

typedef unsigned short u16;
typedef unsigned int   u32;
typedef __attribute__((ext_vector_type(8))) short short8;
typedef __attribute__((ext_vector_type(4))) float f32x4;

__device__ __forceinline__ float silu_f(float v) {
    float e = __expf(-v);
    return v * __builtin_amdgcn_rcpf(1.f + e);
}
__device__ __forceinline__ float softplus_f(float v) { return v > 20.f ? v : log1pf(__expf(v)); }
__device__ __forceinline__ u16 f2bf(float f) {
    u32 u = __float_as_uint(f);
    u += 0x7FFFu + ((u >> 16) & 1u);
    return (u16)(u >> 16);
}
__device__ __forceinline__ u32 cvtpk(float lo, float hi) {
    u32 r;
    asm("v_cvt_pk_bf16_f32 %0, %1, %2" : "=v"(r) : "v"(lo), "v"(hi));
    return r;
}
__device__ __forceinline__ float bf2f(u32 u) { return __uint_as_float(u << 16); }

// ---------------------------------------------------------------------------
// Transpose x [C][HW] -> xt [pix][C] bf16.
// ---------------------------------------------------------------------------
__launch_bounds__(256)
__global__ void xpose_k(const float* __restrict__ x, u16* __restrict__ xt)
{
    __shared__ u16 tile[256][66];
    const int pix0 = blockIdx.x * 64;
    const int tid = threadIdx.x;
    const int pl = tid & 63, cq = tid >> 6;
    const int pix = pix0 + pl;
    const bool pv = pix < HWSZ;
#pragma unroll 4
    for (int j = 0; j < 64; ++j) {
        int c = cq * 64 + j;
        float v = pv ? x[(size_t)c * HWSZ + pix] : 0.f;
        tile[c][pl] = f2bf(v);
    }
    __syncthreads();
    for (int i = 0; i < 64; ++i) {
        int p2 = pix0 + i;
        if (p2 < HWSZ) xt[(size_t)p2 * 256 + tid] = tile[tid][i];
    }
}

__global__ void zero2_k(u16* __restrict__ p, size_t zstride, int n)
{
    int i = blockIdx.x * 256 + threadIdx.x;
    if (i < n) p[(size_t)blockIdx.y * zstride + i] = 0;
}

__global__ void convpad2_k(const float* __restrict__ s0, const float* __restrict__ s1,
                           u16* __restrict__ dst, int rows, int cols, size_t zstride)
{
    const int z = blockIdx.y;
    const float* __restrict__ src = z ? s1 : s0;
    u16* __restrict__ d = dst + (size_t)z * zstride;
    int r = blockIdx.x;
    for (int c = threadIdx.x; c < cols; c += 256)
        d[(size_t)r * cols + c] = (r < rows) ? f2bf(src[(size_t)r * cols + c]) : (u16)0;
}

// ---------------------------------------------------------------------------
// W-stationary streaming GEMM v2 (TM=32, launch_bounds(512,4)).
// ---------------------------------------------------------------------------
template<int MODE, int K, int NFRAG, int NPANEL, int G>
__launch_bounds__(512, 4)
__global__ void wsgemm_k(const u16* __restrict__ A, const u16* __restrict__ W,
                         u16* __restrict__ outB, u16* __restrict__ zxb,
                         float* __restrict__ tail)
{
    constexpr int KS = K / 32;
    constexpr int SLOTS = K / 8;
    constexpr int LOADS = (32 * SLOTS) / 512;
    __shared__ u16 As[32 * K];

    const int nwg = NPANEL * G;
    const int orig = blockIdx.x;
    const int xcd = orig & 7;
    const int q = nwg >> 3, r = nwg & 7;
    const int wgid = (xcd < r ? xcd * (q + 1) : r * (q + 1) + (xcd - r) * q) + (orig >> 3);
    const int panel = wgid % NPANEL;
    const int t0 = wgid / NPANEL;

    const int tid = threadIdx.x;
    const int lane = tid & 63, wn = tid >> 6;
    const int rl15 = lane & 15, kg = lane >> 4;
    const int c0 = panel * (NFRAG * 128);
    const int NT = MPAD / 32;

    short8 wf[NFRAG][KS];
#pragma unroll
    for (int f = 0; f < NFRAG; ++f) {
        const int row = c0 + (wn * NFRAG + f) * 16 + rl15;
#pragma unroll
        for (int ks = 0; ks < KS; ++ks)
            wf[f][ks] = *(const short8*)(W + (size_t)row * K + ks * 32 + kg * 8);
    }

    auto loadregs = [&](int t, uint4* st) {
        const u16* src = A + (size_t)t * 32 * K;
#pragma unroll
        for (int i = 0; i < LOADS; ++i) {
            int ch = i * 512 + tid;
            int row = ch / SLOTS, sl = ch % SLOTS;
            st[i] = *(const uint4*)(src + (size_t)row * K + sl * 8);
        }
    };
    auto dswrite = [&](uint4* st) {
#pragma unroll
        for (int i = 0; i < LOADS; ++i) {
            int ch = i * 512 + tid;
            int row = ch / SLOTS, sl = ch % SLOTS;
            *(uint4*)((char*)As + row * (K * 2) + ((sl ^ (row & 7)) * 16)) = st[i];
        }
    };

    uint4 st[LOADS];
    loadregs(t0, st);
    dswrite(st);
    asm volatile("s_waitcnt lgkmcnt(0)" ::: "memory");
    __builtin_amdgcn_sched_barrier(0);
    __builtin_amdgcn_s_barrier();

    for (int t = t0; t < NT; t += G) {
        const bool hn = (t + G) < NT;
        if (hn) loadregs(t + G, st);

        f32x4 acc[2][NFRAG];
#pragma unroll
        for (int rr = 0; rr < 2; ++rr)
#pragma unroll
            for (int f = 0; f < NFRAG; ++f)
                acc[rr][f] = (f32x4){0.f, 0.f, 0.f, 0.f};

        __builtin_amdgcn_s_setprio(1);
#pragma unroll
        for (int ks = 0; ks < KS; ++ks) {
            short8 a[2];
#pragma unroll
            for (int rr = 0; rr < 2; ++rr) {
                int row = rr * 16 + rl15;
                int sw = (ks * 4 + kg) ^ (row & 7);
                a[rr] = *(const short8*)((const char*)As + row * (K * 2) + sw * 16);
            }
#pragma unroll
            for (int rr = 0; rr < 2; ++rr)
#pragma unroll
                for (int f = 0; f < NFRAG; ++f)
                    acc[rr][f] = __builtin_amdgcn_mfma_f32_16x16x32_bf16(a[rr], wf[f][ks], acc[rr][f], 0, 0, 0);
        }
        __builtin_amdgcn_s_setprio(0);
        __builtin_amdgcn_s_barrier();
        if (hn) {
            dswrite(st);
            asm volatile("s_waitcnt lgkmcnt(0)" ::: "memory");
            __builtin_amdgcn_sched_barrier(0);
        }
        __builtin_amdgcn_s_barrier();

#pragma unroll
        for (int rr = 0; rr < 2; ++rr) {
#pragma unroll
            for (int f = 0; f < NFRAG; ++f) {
                const int col = c0 + (wn * NFRAG + f) * 16 + rl15;
#pragma unroll
                for (int ri = 0; ri < 4; ++ri) {
                    const int gl = t * 32 + rr * 16 + kg * 4 + ri;
                    if (gl >= L_SEQ) continue;
                    float v = acc[rr][f][ri];
                    if (MODE == 0) {
                        outB[(size_t)gl * 256 + col] = (u16)cvtpk(v, v);
                    } else {
                        int zp = (col >= 640) ? 1 : 0;
                        int c6 = col - zp * 640;
                        if (c6 < 512) {
                            float s = silu_f(v);
                            zxb[(size_t)zp * L_SEQ * 512 + (size_t)gl * 512 + c6] = (u16)cvtpk(s, s);
                        } else if (c6 < 520) {
                            tail[(size_t)zp * L_SEQ * 12 + (size_t)gl * 12 + (c6 - 512)] = silu_f(v);
                        } else if (c6 < 524) {
                            tail[(size_t)zp * L_SEQ * 12 + (size_t)gl * 12 + (c6 - 512)] = v;
                        }
                    }
                }
            }
        }
    }
}

// ---------------------------------------------------------------------------
// Out-proj GEMM with FUSED LayerNorm + transpose epilogue.
// ---------------------------------------------------------------------------
template<int G>
__launch_bounds__(1024, 2)
__global__ void wsgemmLN_k(const u16* __restrict__ A, const u16* __restrict__ W,
                           const float* __restrict__ lng, const float* __restrict__ lnb_,
                           float* __restrict__ out)
{
    constexpr int K = 512;
    constexpr int KS = K / 32;
    constexpr int SLOTS = K / 8;
    constexpr int LOADS = (32 * SLOTS) / 1024;
    __shared__ u16 As[32 * K];
    __shared__ float lnb[32][257];
    __shared__ float mu_s[32], rs_s[32];

    const int nwg = G;
    const int orig = blockIdx.x;
    const int xcd = orig & 7;
    const int q = nwg >> 3, r = nwg & 7;
    const int wgid = (xcd < r ? xcd * (q + 1) : r * (q + 1) + (xcd - r) * q) + (orig >> 3);
    const int t0 = wgid;

    const int tid = threadIdx.x;
    const int lane = tid & 63, wn = tid >> 6;
    const int rl15 = lane & 15, kg = lane >> 4;
    const int col = wn * 16 + rl15;
    const int NT = MPAD / 32;

    short8 wf[KS];
#pragma unroll
    for (int ks = 0; ks < KS; ++ks)
        wf[ks] = *(const short8*)(W + (size_t)col * K + ks * 32 + kg * 8);

    auto loadregs = [&](int t, uint4* st) {
        const u16* src = A + (size_t)t * 32 * K;
#pragma unroll
        for (int i = 0; i < LOADS; ++i) {
            int ch = i * 1024 + tid;
            int row = ch >> 6, sl = ch & 63;
            st[i] = *(const uint4*)(src + (size_t)row * K + sl * 8);
        }
    };
    auto dswrite = [&](uint4* st) {
#pragma unroll
        for (int i = 0; i < LOADS; ++i) {
            int ch = i * 1024 + tid;
            int row = ch >> 6, sl = ch & 63;
            *(uint4*)((char*)As + row * (K * 2) + ((sl ^ (row & 7)) * 16)) = st[i];
        }
    };

    const int chW = tid >> 2, pqW = tid & 3;
    const float gch = lng[chW], bch = lnb_[chW];

    uint4 st[LOADS];
    loadregs(t0, st);
    dswrite(st);
    asm volatile("s_waitcnt lgkmcnt(0)" ::: "memory");
    __builtin_amdgcn_sched_barrier(0);
    __builtin_amdgcn_s_barrier();

    for (int t = t0; t < NT; t += G) {
        const bool hn = (t + G) < NT;
        if (hn) loadregs(t + G, st);

        f32x4 acc[2];
        acc[0] = (f32x4){0.f, 0.f, 0.f, 0.f};
        acc[1] = (f32x4){0.f, 0.f, 0.f, 0.f};

        __builtin_amdgcn_s_setprio(1);
#pragma unroll
        for (int ks = 0; ks < KS; ++ks) {
            short8 a[2];
#pragma unroll
            for (int rr = 0; rr < 2; ++rr) {
                int row = rr * 16 + rl15;
                int sw = (ks * 4 + kg) ^ (row & 7);
                a[rr] = *(const short8*)((const char*)As + row * (K * 2) + sw * 16);
            }
#pragma unroll
            for (int rr = 0; rr < 2; ++rr)
                acc[rr] = __builtin_amdgcn_mfma_f32_16x16x32_bf16(a[rr], wf[ks], acc[rr], 0, 0, 0);
        }
        __builtin_amdgcn_s_setprio(0);
        __builtin_amdgcn_s_barrier();
        if (hn) {
            dswrite(st);
            asm volatile("s_waitcnt lgkmcnt(0)" ::: "memory");
            __builtin_amdgcn_sched_barrier(0);
        }
        __builtin_amdgcn_s_barrier();

#pragma unroll
        for (int rr = 0; rr < 2; ++rr)
#pragma unroll
            for (int ri = 0; ri < 4; ++ri)
                lnb[rr * 16 + kg * 4 + ri][col] = acc[rr][ri];
        __syncthreads();

        {
            const int row = tid >> 5, cg = tid & 31;
            float s = 0.f, s2 = 0.f;
#pragma unroll
            for (int j = 0; j < 8; ++j) {
                float v = lnb[row][cg + j * 32];
                s += v; s2 += v * v;
            }
#pragma unroll
            for (int o = 16; o > 0; o >>= 1) {
                s += __shfl_xor(s, o, 32);
                s2 += __shfl_xor(s2, o, 32);
            }
            if (cg == 0) {
                float mu = s * (1.f / 256.f);
                float var = s2 * (1.f / 256.f) - mu * mu;
                mu_s[row] = mu;
                rs_s[row] = rsqrtf(var + 1e-6f);
            }
        }
        __syncthreads();

        {
            const int pixBase = t * 32 + pqW * 8;
            if (pixBase + 8 <= HWSZ) {
                float o0[8];
#pragma unroll
                for (int j = 0; j < 8; ++j) {
                    const int pl = pqW * 8 + j;
                    o0[j] = (lnb[pl][chW] - mu_s[pl]) * rs_s[pl] * gch + bch;
                }
                float* op = out + (size_t)chW * HWSZ + pixBase;
                *(float4*)(op)     = make_float4(o0[0], o0[1], o0[2], o0[3]);
                *(float4*)(op + 4) = make_float4(o0[4], o0[5], o0[6], o0[7]);
            } else {
                for (int j = 0; j < 8; ++j) {
                    const int pix = pixBase + j;
                    if (pix < HWSZ) {
                        const int pl = pqW * 8 + j;
                        out[(size_t)chW * HWSZ + pix] =
                            (lnb[pl][chW] - mu_s[pl]) * rs_s[pl] * gch + bch;
                    }
                }
            }
        }
        __syncthreads();
    }
}

// ---------------------------------------------------------------------------
// Per-chunk prep.
// ---------------------------------------------------------------------------
__launch_bounds__(256)
__global__ void prep_k(const float* __restrict__ tail, const float* __restrict__ db0,
                       const float* __restrict__ db1, const float* __restrict__ al0,
                       const float* __restrict__ al1, const int* __restrict__ mor0,
                       const int* __restrict__ mor1, float* __restrict__ dtb,
                       float* __restrict__ acsb, float* __restrict__ csum)
{
    const int z = blockIdx.y;
    const float* dt_bias = z ? db1 : db0;
    const float* A_log = z ? al1 : al0;
    const int* mor = z ? mor1 : mor0;
    const float* tl = tail + (size_t)z * L_SEQ * 12;
    float* dtbp = dtb + (size_t)z * L_SEQ * 4;
    float* acsp = acsb + (size_t)z * L_SEQ * 4;
    float* csp = csum + (size_t)z * NCH * 4;

    const int c = blockIdx.x;
    const int l = threadIdx.x;
    const int lane = l & 63, w = l >> 6;
    const int gl = c * 256 + l;
    const bool valid = gl < L_SEQ;
    float v[NH] = {0.f, 0.f, 0.f, 0.f};
    if (valid) {
        const int pos = mor[gl];
        float4 dv = *(const float4*)(tl + (size_t)pos * 12 + 8);
        const float* dp = (const float*)&dv;
#pragma unroll
        for (int h = 0; h < NH; ++h) {
            float dt = softplus_f(dp[h] + dt_bias[h]);
            dtbp[(size_t)gl * 4 + h] = dt;
            v[h] = -__expf(A_log[h]) * LOG2E * dt;
        }
    }
#pragma unroll
    for (int off = 1; off < 64; off <<= 1) {
#pragma unroll
        for (int h = 0; h < NH; ++h) {
            float tt = __shfl_up(v[h], off, 64);
            if (lane >= off) v[h] += tt;
        }
    }
    __shared__ float wsum[4][NH];
    if (lane == 63)
#pragma unroll
        for (int h = 0; h < NH; ++h) wsum[w][h] = v[h];
    __syncthreads();
#pragma unroll
    for (int h = 0; h < NH; ++h) {
        float o = 0.f;
#pragma unroll
        for (int w2 = 0; w2 < 4; ++w2) if (w2 < w) o += wsum[w2][h];
        v[h] += o;
    }
    if (valid)
#pragma unroll
        for (int h = 0; h < NH; ++h) acsp[(size_t)gl * 4 + h] = v[h];
    if (l == 255)
#pragma unroll
        for (int h = 0; h < NH; ++h) csp[c * 4 + h] = v[h];
}

// ---------------------------------------------------------------------------
// Chunk-end states, partial.
// ---------------------------------------------------------------------------
__launch_bounds__(256)
__global__ void states_part_k(const u16* __restrict__ zxb, const float* __restrict__ dtb,
                              const float* __restrict__ tail, const float* __restrict__ acsb,
                              const float* __restrict__ csum, const int* __restrict__ mor0,
                              const int* __restrict__ mor1, float* __restrict__ spart)
{
    const int z = blockIdx.z;
    const u16* zxp = zxb + (size_t)z * L_SEQ * 512;
    const float* dtbp = dtb + (size_t)z * L_SEQ * 4;
    const float* tl = tail + (size_t)z * L_SEQ * 12;
    const float* acsp = acsb + (size_t)z * L_SEQ * 4;
    const float* csp = csum + (size_t)z * NCH * 4;
    const int* mor = z ? mor1 : mor0;
    float* spp = spart + (size_t)z * NCH * 4096;

    __shared__ float coef[64][16];
    __shared__ int posL[64];
    const int c = blockIdx.x, q = blockIdx.y;
    const int tid = threadIdx.x;
    {
        const int l_loc = tid >> 2, h = tid & 3;
        const int gl = c * 256 + q * 64 + l_loc;
        const int pos = (gl < L_SEQ) ? mor[gl] : 0;
        float4 Bv = make_float4(0.f, 0.f, 0.f, 0.f);
        float e = 0.f;
        if (gl < L_SEQ) {
            Bv = *(const float4*)(tl + (size_t)pos * 12);
            e = exp2f(csp[c * 4 + h] - acsp[(size_t)gl * 4 + h]) * dtbp[(size_t)gl * 4 + h];
        }
        *(float4*)&coef[l_loc][h * 4] = make_float4(Bv.x * e, Bv.y * e, Bv.z * e, Bv.w * e);
        if (h == 0) posL[l_loc] = pos;
    }
    __syncthreads();
    const int h = tid >> 6;
    f32x4 acc = (f32x4){0.f, 0.f, 0.f, 0.f};
#pragma unroll 4
    for (int j = 0; j < 64; ++j) {
        const int gl = c * 256 + q * 64 + j;
        float xs = 0.f;
        if (gl < L_SEQ) xs = bf2f(zxp[(size_t)posL[j] * 512 + 256 + tid]);
        float4 cf = *(const float4*)&coef[j][h * 4];
        acc[0] += cf.x * xs; acc[1] += cf.y * xs;
        acc[2] += cf.z * xs; acc[3] += cf.w * xs;
    }
    *(f32x4*)(spp + ((size_t)(c * 4 + q) * 256 + tid) * 4) = acc;
}

// ---------------------------------------------------------------------------
// Inter-chunk scan with fused q-reduction.
// ---------------------------------------------------------------------------
__launch_bounds__(256)
__global__ void chunkscan_k(const float* __restrict__ csum, const float* __restrict__ spart,
                            float* __restrict__ prev)
{
    const int z = blockIdx.y;
    const float* csp = csum + (size_t)z * NCH * 4;
    const float* spp = spart + (size_t)z * NCH * 4096;
    float* prp = prev + (size_t)z * NCH * 1024;

    const int h = blockIdx.x;
    const int tid = threadIdx.x;
    __shared__ float ecs[NCH];
    if (tid < NCH) ecs[tid] = exp2f(csp[tid * 4 + h]);
    __syncthreads();
    float run = 0.f;
#pragma unroll 2
    for (int c = 0; c < NCH; ++c) {
        const float* sp = spp + (size_t)(c * 4) * 1024 + h * 256 + tid;
        float s = sp[0] + sp[1024] + sp[2048] + sp[3072];
        prp[(size_t)c * 1024 + h * 256 + tid] = run;
        run = run * ecs[c] + s;
    }
}

// ---------------------------------------------------------------------------
// MFMA per-chunk output v4.1 (exp-factored).
// ---------------------------------------------------------------------------
__launch_bounds__(1024, 4)
__global__ void ychunk4_k(const u16* __restrict__ zxb, const float* __restrict__ tail,
                          const float* __restrict__ dtb, const float* __restrict__ acsb,
                          const float* __restrict__ prev, const float* __restrict__ Dv0,
                          const float* __restrict__ Dv1, const int* __restrict__ mor0,
                          const int* __restrict__ mor1, u16* __restrict__ cat)
{
    const int z = blockIdx.z;
    const u16* zxp = zxb + (size_t)z * L_SEQ * 512;
    const float* tl = tail + (size_t)z * L_SEQ * 12;
    const float* dtbp = dtb + (size_t)z * L_SEQ * 4;
    const float* acsp = acsb + (size_t)z * L_SEQ * 4;
    const float* prp = prev + (size_t)z * NCH * 1024;
    const float* Dv = z ? Dv1 : Dv0;
    const int* mor = z ? mor1 : mor0;
    const int catOff = z * 256;

    __shared__ __align__(16) u16 Xt[64 * 256];
    __shared__ __align__(16) u16 Xp[64 * 40];
    __shared__ float4 sBdt[256];
    __shared__ float4 sC[256];
    __shared__ float  sA2[256];
    __shared__ int    morL[256];

    const int c = blockIdx.x, h = blockIdx.y;
    const int tid = threadIdx.x;
    const int lane = tid & 63, w = tid >> 6;     // w = 0..15

    if (tid < 256) {
        const int s = tid, gl = c * 256 + s;
        const int pos = (gl < L_SEQ) ? mor[gl] : 0;
        morL[s] = pos;
        if (gl < L_SEQ) {
            const float* tr = tl + (size_t)pos * 12;
            float4 B4 = *(const float4*)tr;
            float4 C4v = *(const float4*)(tr + 4);
            float dt = dtbp[(size_t)gl * 4 + h];
            sBdt[s] = make_float4(B4.x * dt, B4.y * dt, B4.z * dt, B4.w * dt);
            sC[s] = C4v;
            sA2[s] = acsp[(size_t)gl * 4 + h];
        } else {
            sBdt[s] = make_float4(0.f, 0.f, 0.f, 0.f);
            sC[s] = make_float4(0.f, 0.f, 0.f, 0.f);
            sA2[s] = 0.f;
        }
    } else if (tid < 320) {
        int i = tid - 256;
        float4 pv = *(const float4*)(prp + (size_t)c * 1024 + h * 256 + i * 4);
        u32 w0 = cvtpk(pv.x, pv.y), w1 = cvtpk(pv.z, pv.w);
        uint4* row = (uint4*)((char*)Xp + i * 80);
        row[0] = make_uint4(w0, w1, 0u, 0u);
        row[1] = make_uint4(0u, 0u, 0u, 0u);
        row[2] = make_uint4(0u, 0u, 0u, 0u);
        row[3] = make_uint4(0u, 0u, 0u, 0u);
    }
    __syncthreads();

    if (tid < 256) {
        const int s = tid;
        float es = exp2f(sA2[s & ~7] - sA2[s]);
        float4 b4 = sBdt[s];
        sBdt[s] = make_float4(b4.x * es, b4.y * es, b4.z * es, b4.w * es);
    }
    {
        const int p = lane;
        const size_t colOff = 256 + h * 64 + p;
#pragma unroll
        for (int jq = 0; jq < 2; ++jq) {
            const int s0 = w * 16 + jq * 8;
            u32 wd[4];
#pragma unroll
            for (int q2 = 0; q2 < 4; ++q2) {
                int sIdx = s0 + q2 * 2;
                int gl0 = c * 256 + sIdx;
                u32 lo = (gl0     < L_SEQ) ? (u32)zxp[(size_t)morL[sIdx] * 512 + colOff] : 0u;
                u32 hi = (gl0 + 1 < L_SEQ) ? (u32)zxp[(size_t)morL[sIdx + 1] * 512 + colOff] : 0u;
                wd[q2] = lo | (hi << 16);
            }
            u32 off = (u32)(p * 512 + s0 * 2) ^ (u32)((p & 15) << 4);
            *(uint4*)((char*)Xt + off) = make_uint4(wd[0], wd[1], wd[2], wd[3]);
        }
    }
    __syncthreads();

    const int rl15 = lane & 15, kg = lane >> 4;
    const int R = w * 16;
    const int km = w >> 1;
    const float Dh = Dv[h];
    const int lrow = R + rl15;
    const float4 C4 = sC[lrow];
    const float al2 = sA2[lrow];

    f32x4 acc[4];
#pragma unroll
    for (int n = 0; n < 4; ++n) acc[n] = (f32x4){0.f, 0.f, 0.f, 0.f};

    for (int ks = 0; ks <= km; ++ks) {
        const int s0 = ks * 32 + kg * 8;
        short8 bf[4];
#pragma unroll
        for (int n = 0; n < 4; ++n) {
            int col = n * 16 + rl15;
            u32 off = (u32)(col * 512 + ks * 64 + kg * 16) ^ (u32)((col & 15) << 4);
            bf[n] = *(const short8*)((const char*)Xt + off);
        }
        const float eL = exp2f(al2 - sA2[s0]);
        float4 Bv[8];
#pragma unroll
        for (int j = 0; j < 8; ++j) Bv[j] = sBdt[s0 + j];
        float vv[8];
        if (ks < km) {
#pragma unroll
            for (int j = 0; j < 8; ++j) {
                float dot = C4.x * Bv[j].x + C4.y * Bv[j].y
                          + C4.z * Bv[j].z + C4.w * Bv[j].w;
                vv[j] = dot * eL;
            }
        } else {
#pragma unroll
            for (int j = 0; j < 8; ++j) {
                int s = s0 + j;
                float dot = C4.x * Bv[j].x + C4.y * Bv[j].y
                          + C4.z * Bv[j].z + C4.w * Bv[j].w;
                float v = dot * eL;
                v = (s <= lrow) ? v : 0.f;
                vv[j] = (s == lrow) ? v + Dh : v;
            }
        }
        union { u32 wd[4]; short8 v; } aw;
#pragma unroll
        for (int q2 = 0; q2 < 4; ++q2) aw.wd[q2] = cvtpk(vv[2 * q2], vv[2 * q2 + 1]);
#pragma unroll
        for (int n = 0; n < 4; ++n)
            acc[n] = __builtin_amdgcn_mfma_f32_16x16x32_bf16(aw.v, bf[n], acc[n], 0, 0, 0);
    }
    {
        short8 bp[4];
#pragma unroll
        for (int n = 0; n < 4; ++n) {
            int col = n * 16 + rl15;
            bp[n] = *(const short8*)((const char*)Xp + col * 80 + kg * 16);
        }
        float ea = exp2f(al2);
        union { u32 wd[4]; short8 v; } aw;
        aw.wd[0] = (kg == 0) ? cvtpk(ea * C4.x, ea * C4.y) : 0u;
        aw.wd[1] = (kg == 0) ? cvtpk(ea * C4.z, ea * C4.w) : 0u;
        aw.wd[2] = 0u; aw.wd[3] = 0u;
#pragma unroll
        for (int n = 0; n < 4; ++n)
            acc[n] = __builtin_amdgcn_mfma_f32_16x16x32_bf16(aw.v, bp[n], acc[n], 0, 0, 0);
    }

#pragma unroll
    for (int r = 0; r < 4; ++r) {
        const int row = R + kg * 4 + r;
        const int gl = c * 256 + row;
        if (gl >= L_SEQ) continue;
        const int pos = morL[row];
        const size_t zbase = (size_t)pos * 512 + h * 64;
        u16* orow = cat + (size_t)pos * 512 + catOff + h * 64;
#pragma unroll
        for (int n = 0; n < 4; ++n) {
            const int col = n * 16 + rl15;
            float zs = bf2f(zxp[zbase + col]);
            float y = acc[n][r] * zs;
            orow[col] = (u16)cvtpk(y, y);
        }
    }
}

// ---------------------------------------------------------------------------
extern "C" void kernel_launch(void* const* d_in, const int* in_sizes, int n_in,
                              void* d_out, int out_size, void* d_ws, size_t ws_size,
                              hipStream_t stream)
{
    const float* x      = (const float*)d_in[0];
    const float* W_in0  = (const float*)d_in[1];
    const float* W_in1  = (const float*)d_in[2];
    const float* dt_b0  = (const float*)d_in[3];
    const float* dt_b1  = (const float*)d_in[4];
    const float* A_log0 = (const float*)d_in[5];
    const float* A_log1 = (const float*)d_in[6];
    const float* Dv0    = (const float*)d_in[7];
    const float* Dv1    = (const float*)d_in[8];
    const float* W_out  = (const float*)d_in[9];
    const float* ln_g   = (const float*)d_in[10];
    const float* ln_b   = (const float*)d_in[11];
    const int*   mor0   = (const int*)d_in[12];
    const int*   mor1   = (const int*)d_in[13];

    char* ws = (char*)d_ws;
    size_t off = 0;
    auto alloc = [&](size_t bytes) { char* p = ws + off; off += (bytes + 255) & ~(size_t)255; return p; };
    u16*   xt    = (u16*)  alloc((size_t)MPAD * 256 * 2);
    u16*   zxb   = (u16*)  alloc((size_t)2 * L_SEQ * 512 * 2);
    u16*   cat   = (u16*)  alloc((size_t)MPAD * 512 * 2);
    float* tail  = (float*)alloc((size_t)2 * L_SEQ * 12 * 4);
    u16*   wbufI = (u16*)  alloc((size_t)1280 * 256 * 2);
    u16*   wbufO = (u16*)  alloc((size_t)256 * 512 * 2);
    float* dtb   = (float*)alloc((size_t)2 * L_SEQ * 4 * 4);
    float* acsb  = (float*)alloc((size_t)2 * L_SEQ * 4 * 4);
    float* csum  = (float*)alloc((size_t)2 * NCH * 4 * 4);
    float* spart = (float*)alloc((size_t)2 * NCH * 4096 * 4);
    float* prev  = (float*)alloc((size_t)2 * NCH * 1024 * 4);

    convpad2_k<<<dim3(640, 2), 256, 0, stream>>>(W_in0, W_in1, wbufI, 524, 256, (size_t)640 * 256);
    convpad2_k<<<dim3(256, 1), 256, 0, stream>>>(W_out, W_out, wbufO, 256, 512, 0);
    xpose_k<<<507, 256, 0, stream>>>(x, xt);
    zero2_k<<<dim3(112, 1), 256, 0, stream>>>(xt + (size_t)L_SEQ * 256, 0, 112 * 256);

    // merged in-proj: M=32512, N=1280, K=256
    wsgemm_k<1, 256, 2, 5, 102><<<510, 512, 0, stream>>>(xt, wbufI, nullptr, zxb, tail);

    prep_k<<<dim3(NCH, 2), 256, 0, stream>>>(tail, dt_b0, dt_b1, A_log0, A_log1,
                                             mor0, mor1, dtb, acsb, csum);
    states_part_k<<<dim3(NCH, 4, 2), 256, 0, stream>>>(zxb, dtb, tail, acsb, csum,
                                                       mor0, mor1, spart);
    chunkscan_k<<<dim3(4, 2), 256, 0, stream>>>(csum, spart, prev);
    ychunk4_k<<<dim3(NCH, NH, 2), 1024, 0, stream>>>(zxb, tail, dtb, acsb, prev,
                                                     Dv0, Dv1, mor0, mor1, cat);

    zero2_k<<<dim3(224, 1), 256, 0, stream>>>(cat + (size_t)L_SEQ * 512, 0, 112 * 512);
    // out-proj + fused LayerNorm + transpose: M=32512, N=256, K=512
    wsgemmLN_k<508><<<508, 1024, 0, stream>>>(cat, wbufO, ln_g, ln_b, (float*)d_out);
}

// Round 25
// 245.343 us; speedup vs baseline: 1.0739x; 1.0014x over previous
//
#include <hip/hip_runtime.h>
#include <cstdint>

#define L_SEQ 32400
#define HWSZ  32400
#define MPAD  32512
#define NCH   127
#define NH    4
#define LOG2E 1.4426950408889634f

typedef unsigned short u16;
typedef unsigned int   u32;
typedef __attribute__((ext_vector_type(8))) short short8;
typedef __attribute__((ext_vector_type(4))) float f32x4;

__device__ __forceinline__ float silu_f(float v) {
    float e = __expf(-v);
    return v * __builtin_amdgcn_rcpf(1.f + e);
}
__device__ __forceinline__ float softplus_f(float v) { return v > 20.f ? v : log1pf(__expf(v)); }
__device__ __forceinline__ u16 f2bf(float f) {
    u32 u = __float_as_uint(f);
    u += 0x7FFFu + ((u >> 16) & 1u);
    return (u16)(u >> 16);
}
__device__ __forceinline__ u32 cvtpk(float lo, float hi) {
    u32 r;
    asm("v_cvt_pk_bf16_f32 %0, %1, %2" : "=v"(r) : "v"(lo), "v"(hi));
    return r;
}
__device__ __forceinline__ float bf2f(u32 u) { return __uint_as_float(u << 16); }

// ---------------------------------------------------------------------------
// Transpose x [C][HW] -> xt [pix][C] bf16.
// ---------------------------------------------------------------------------
__launch_bounds__(256)
__global__ void xpose_k(const float* __restrict__ x, u16* __restrict__ xt)
{
    __shared__ u16 tile[256][66];
    const int pix0 = blockIdx.x * 64;
    const int tid = threadIdx.x;
    const int pl = tid & 63, cq = tid >> 6;
    const int pix = pix0 + pl;
    const bool pv = pix < HWSZ;
#pragma unroll 4
    for (int j = 0; j < 64; ++j) {
        int c = cq * 64 + j;
        float v = pv ? x[(size_t)c * HWSZ + pix] : 0.f;
        tile[c][pl] = f2bf(v);
    }
    __syncthreads();
    for (int i = 0; i < 64; ++i) {
        int p2 = pix0 + i;
        if (p2 < HWSZ) xt[(size_t)p2 * 256 + tid] = tile[tid][i];
    }
}

__global__ void zero2_k(u16* __restrict__ p, size_t zstride, int n)
{
    int i = blockIdx.x * 256 + threadIdx.x;
    if (i < n) p[(size_t)blockIdx.y * zstride + i] = 0;
}

__global__ void convpad2_k(const float* __restrict__ s0, const float* __restrict__ s1,
                           u16* __restrict__ dst, int rows, int cols, size_t zstride)
{
    const int z = blockIdx.y;
    const float* __restrict__ src = z ? s1 : s0;
    u16* __restrict__ d = dst + (size_t)z * zstride;
    int r = blockIdx.x;
    for (int c = threadIdx.x; c < cols; c += 256)
        d[(size_t)r * cols + c] = (r < rows) ? f2bf(src[(size_t)r * cols + c]) : (u16)0;
}

// ---------------------------------------------------------------------------
// W-stationary streaming GEMM v2 (TM=32, launch_bounds(512,4)).
// ---------------------------------------------------------------------------
template<int MODE, int K, int NFRAG, int NPANEL, int G>
__launch_bounds__(512, 4)
__global__ void wsgemm_k(const u16* __restrict__ A, const u16* __restrict__ W,
                         u16* __restrict__ outB, u16* __restrict__ zxb,
                         float* __restrict__ tail)
{
    constexpr int KS = K / 32;
    constexpr int SLOTS = K / 8;
    constexpr int LOADS = (32 * SLOTS) / 512;
    __shared__ u16 As[32 * K];

    const int nwg = NPANEL * G;
    const int orig = blockIdx.x;
    const int xcd = orig & 7;
    const int q = nwg >> 3, r = nwg & 7;
    const int wgid = (xcd < r ? xcd * (q + 1) : r * (q + 1) + (xcd - r) * q) + (orig >> 3);
    const int panel = wgid % NPANEL;
    const int t0 = wgid / NPANEL;

    const int tid = threadIdx.x;
    const int lane = tid & 63, wn = tid >> 6;
    const int rl15 = lane & 15, kg = lane >> 4;
    const int c0 = panel * (NFRAG * 128);
    const int NT = MPAD / 32;

    short8 wf[NFRAG][KS];
#pragma unroll
    for (int f = 0; f < NFRAG; ++f) {
        const int row = c0 + (wn * NFRAG + f) * 16 + rl15;
#pragma unroll
        for (int ks = 0; ks < KS; ++ks)
            wf[f][ks] = *(const short8*)(W + (size_t)row * K + ks * 32 + kg * 8);
    }

    auto loadregs = [&](int t, uint4* st) {
        const u16* src = A + (size_t)t * 32 * K;
#pragma unroll
        for (int i = 0; i < LOADS; ++i) {
            int ch = i * 512 + tid;
            int row = ch / SLOTS, sl = ch % SLOTS;
            st[i] = *(const uint4*)(src + (size_t)row * K + sl * 8);
        }
    };
    auto dswrite = [&](uint4* st) {
#pragma unroll
        for (int i = 0; i < LOADS; ++i) {
            int ch = i * 512 + tid;
            int row = ch / SLOTS, sl = ch % SLOTS;
            *(uint4*)((char*)As + row * (K * 2) + ((sl ^ (row & 7)) * 16)) = st[i];
        }
    };

    uint4 st[LOADS];
    loadregs(t0, st);
    dswrite(st);
    asm volatile("s_waitcnt lgkmcnt(0)" ::: "memory");
    __builtin_amdgcn_sched_barrier(0);
    __builtin_amdgcn_s_barrier();

    for (int t = t0; t < NT; t += G) {
        const bool hn = (t + G) < NT;
        if (hn) loadregs(t + G, st);

        f32x4 acc[2][NFRAG];
#pragma unroll
        for (int rr = 0; rr < 2; ++rr)
#pragma unroll
            for (int f = 0; f < NFRAG; ++f)
                acc[rr][f] = (f32x4){0.f, 0.f, 0.f, 0.f};

        __builtin_amdgcn_s_setprio(1);
#pragma unroll
        for (int ks = 0; ks < KS; ++ks) {
            short8 a[2];
#pragma unroll
            for (int rr = 0; rr < 2; ++rr) {
                int row = rr * 16 + rl15;
                int sw = (ks * 4 + kg) ^ (row & 7);
                a[rr] = *(const short8*)((const char*)As + row * (K * 2) + sw * 16);
            }
#pragma unroll
            for (int rr = 0; rr < 2; ++rr)
#pragma unroll
                for (int f = 0; f < NFRAG; ++f)
                    acc[rr][f] = __builtin_amdgcn_mfma_f32_16x16x32_bf16(a[rr], wf[f][ks], acc[rr][f], 0, 0, 0);
        }
        __builtin_amdgcn_s_setprio(0);
        __builtin_amdgcn_s_barrier();
        if (hn) {
            dswrite(st);
            asm volatile("s_waitcnt lgkmcnt(0)" ::: "memory");
            __builtin_amdgcn_sched_barrier(0);
        }
        __builtin_amdgcn_s_barrier();

#pragma unroll
        for (int rr = 0; rr < 2; ++rr) {
#pragma unroll
            for (int f = 0; f < NFRAG; ++f) {
                const int col = c0 + (wn * NFRAG + f) * 16 + rl15;
#pragma unroll
                for (int ri = 0; ri < 4; ++ri) {
                    const int gl = t * 32 + rr * 16 + kg * 4 + ri;
                    if (gl >= L_SEQ) continue;
                    float v = acc[rr][f][ri];
                    if (MODE == 0) {
                        outB[(size_t)gl * 256 + col] = (u16)cvtpk(v, v);
                    } else {
                        int zp = (col >= 640) ? 1 : 0;
                        int c6 = col - zp * 640;
                        if (c6 < 512) {
                            float s = silu_f(v);
                            zxb[(size_t)zp * L_SEQ * 512 + (size_t)gl * 512 + c6] = (u16)cvtpk(s, s);
                        } else if (c6 < 520) {
                            tail[(size_t)zp * L_SEQ * 12 + (size_t)gl * 12 + (c6 - 512)] = silu_f(v);
                        } else if (c6 < 524) {
                            tail[(size_t)zp * L_SEQ * 12 + (size_t)gl * 12 + (c6 - 512)] = v;
                        }
                    }
                }
            }
        }
    }
}

// ---------------------------------------------------------------------------
// Out-proj GEMM with FUSED LayerNorm + transpose epilogue.
// ---------------------------------------------------------------------------
template<int G>
__launch_bounds__(1024, 2)
__global__ void wsgemmLN_k(const u16* __restrict__ A, const u16* __restrict__ W,
                           const float* __restrict__ lng, const float* __restrict__ lnb_,
                           float* __restrict__ out)
{
    constexpr int K = 512;
    constexpr int KS = K / 32;
    constexpr int SLOTS = K / 8;
    constexpr int LOADS = (32 * SLOTS) / 1024;
    __shared__ u16 As[32 * K];
    __shared__ float lnb[32][257];
    __shared__ float mu_s[32], rs_s[32];

    const int nwg = G;
    const int orig = blockIdx.x;
    const int xcd = orig & 7;
    const int q = nwg >> 3, r = nwg & 7;
    const int wgid = (xcd < r ? xcd * (q + 1) : r * (q + 1) + (xcd - r) * q) + (orig >> 3);
    const int t0 = wgid;

    const int tid = threadIdx.x;
    const int lane = tid & 63, wn = tid >> 6;
    const int rl15 = lane & 15, kg = lane >> 4;
    const int col = wn * 16 + rl15;
    const int NT = MPAD / 32;

    short8 wf[KS];
#pragma unroll
    for (int ks = 0; ks < KS; ++ks)
        wf[ks] = *(const short8*)(W + (size_t)col * K + ks * 32 + kg * 8);

    auto loadregs = [&](int t, uint4* st) {
        const u16* src = A + (size_t)t * 32 * K;
#pragma unroll
        for (int i = 0; i < LOADS; ++i) {
            int ch = i * 1024 + tid;
            int row = ch >> 6, sl = ch & 63;
            st[i] = *(const uint4*)(src + (size_t)row * K + sl * 8);
        }
    };
    auto dswrite = [&](uint4* st) {
#pragma unroll
        for (int i = 0; i < LOADS; ++i) {
            int ch = i * 1024 + tid;
            int row = ch >> 6, sl = ch & 63;
            *(uint4*)((char*)As + row * (K * 2) + ((sl ^ (row & 7)) * 16)) = st[i];
        }
    };

    const int chW = tid >> 2, pqW = tid & 3;
    const float gch = lng[chW], bch = lnb_[chW];

    uint4 st[LOADS];
    loadregs(t0, st);
    dswrite(st);
    asm volatile("s_waitcnt lgkmcnt(0)" ::: "memory");
    __builtin_amdgcn_sched_barrier(0);
    __builtin_amdgcn_s_barrier();

    for (int t = t0; t < NT; t += G) {
        const bool hn = (t + G) < NT;
        if (hn) loadregs(t + G, st);

        f32x4 acc[2];
        acc[0] = (f32x4){0.f, 0.f, 0.f, 0.f};
        acc[1] = (f32x4){0.f, 0.f, 0.f, 0.f};

        __builtin_amdgcn_s_setprio(1);
#pragma unroll
        for (int ks = 0; ks < KS; ++ks) {
            short8 a[2];
#pragma unroll
            for (int rr = 0; rr < 2; ++rr) {
                int row = rr * 16 + rl15;
                int sw = (ks * 4 + kg) ^ (row & 7);
                a[rr] = *(const short8*)((const char*)As + row * (K * 2) + sw * 16);
            }
#pragma unroll
            for (int rr = 0; rr < 2; ++rr)
                acc[rr] = __builtin_amdgcn_mfma_f32_16x16x32_bf16(a[rr], wf[ks], acc[rr], 0, 0, 0);
        }
        __builtin_amdgcn_s_setprio(0);
        __builtin_amdgcn_s_barrier();
        if (hn) {
            dswrite(st);
            asm volatile("s_waitcnt lgkmcnt(0)" ::: "memory");
            __builtin_amdgcn_sched_barrier(0);
        }
        __builtin_amdgcn_s_barrier();

#pragma unroll
        for (int rr = 0; rr < 2; ++rr)
#pragma unroll
            for (int ri = 0; ri < 4; ++ri)
                lnb[rr * 16 + kg * 4 + ri][col] = acc[rr][ri];
        __syncthreads();

        {
            const int row = tid >> 5, cg = tid & 31;
            float s = 0.f, s2 = 0.f;
#pragma unroll
            for (int j = 0; j < 8; ++j) {
                float v = lnb[row][cg + j * 32];
                s += v; s2 += v * v;
            }
#pragma unroll
            for (int o = 16; o > 0; o >>= 1) {
                s += __shfl_xor(s, o, 32);
                s2 += __shfl_xor(s2, o, 32);
            }
            if (cg == 0) {
                float mu = s * (1.f / 256.f);
                float var = s2 * (1.f / 256.f) - mu * mu;
                mu_s[row] = mu;
                rs_s[row] = rsqrtf(var + 1e-6f);
            }
        }
        __syncthreads();

        {
            const int pixBase = t * 32 + pqW * 8;
            if (pixBase + 8 <= HWSZ) {
                float o0[8];
#pragma unroll
                for (int j = 0; j < 8; ++j) {
                    const int pl = pqW * 8 + j;
                    o0[j] = (lnb[pl][chW] - mu_s[pl]) * rs_s[pl] * gch + bch;
                }
                float* op = out + (size_t)chW * HWSZ + pixBase;
                *(float4*)(op)     = make_float4(o0[0], o0[1], o0[2], o0[3]);
                *(float4*)(op + 4) = make_float4(o0[4], o0[5], o0[6], o0[7]);
            } else {
                for (int j = 0; j < 8; ++j) {
                    const int pix = pixBase + j;
                    if (pix < HWSZ) {
                        const int pl = pqW * 8 + j;
                        out[(size_t)chW * HWSZ + pix] =
                            (lnb[pl][chW] - mu_s[pl]) * rs_s[pl] * gch + bch;
                    }
                }
            }
        }
        __syncthreads();
    }
}

// ---------------------------------------------------------------------------
// Per-chunk prep.
// ---------------------------------------------------------------------------
__launch_bounds__(256)
__global__ void prep_k(const float* __restrict__ tail, const float* __restrict__ db0,
                       const float* __restrict__ db1, const float* __restrict__ al0,
                       const float* __restrict__ al1, const int* __restrict__ mor0,
                       const int* __restrict__ mor1, float* __restrict__ dtb,
                       float* __restrict__ acsb, float* __restrict__ csum)
{
    const int z = blockIdx.y;
    const float* dt_bias = z ? db1 : db0;
    const float* A_log = z ? al1 : al0;
    const int* mor = z ? mor1 : mor0;
    const float* tl = tail + (size_t)z * L_SEQ * 12;
    float* dtbp = dtb + (size_t)z * L_SEQ * 4;
    float* acsp = acsb + (size_t)z * L_SEQ * 4;
    float* csp = csum + (size_t)z * NCH * 4;

    const int c = blockIdx.x;
    const int l = threadIdx.x;
    const int lane = l & 63, w = l >> 6;
    const int gl = c * 256 + l;
    const bool valid = gl < L_SEQ;
    float v[NH] = {0.f, 0.f, 0.f, 0.f};
    if (valid) {
        const int pos = mor[gl];
        float4 dv = *(const float4*)(tl + (size_t)pos * 12 + 8);
        const float* dp = (const float*)&dv;
#pragma unroll
        for (int h = 0; h < NH; ++h) {
            float dt = softplus_f(dp[h] + dt_bias[h]);
            dtbp[(size_t)gl * 4 + h] = dt;
            v[h] = -__expf(A_log[h]) * LOG2E * dt;
        }
    }
#pragma unroll
    for (int off = 1; off < 64; off <<= 1) {
#pragma unroll
        for (int h = 0; h < NH; ++h) {
            float tt = __shfl_up(v[h], off, 64);
            if (lane >= off) v[h] += tt;
        }
    }
    __shared__ float wsum[4][NH];
    if (lane == 63)
#pragma unroll
        for (int h = 0; h < NH; ++h) wsum[w][h] = v[h];
    __syncthreads();
#pragma unroll
    for (int h = 0; h < NH; ++h) {
        float o = 0.f;
#pragma unroll
        for (int w2 = 0; w2 < 4; ++w2) if (w2 < w) o += wsum[w2][h];
        v[h] += o;
    }
    if (valid)
#pragma unroll
        for (int h = 0; h < NH; ++h) acsp[(size_t)gl * 4 + h] = v[h];
    if (l == 255)
#pragma unroll
        for (int h = 0; h < NH; ++h) csp[c * 4 + h] = v[h];
}

// ---------------------------------------------------------------------------
// Chunk-end states, partial.
// ---------------------------------------------------------------------------
__launch_bounds__(256)
__global__ void states_part_k(const u16* __restrict__ zxb, const float* __restrict__ dtb,
                              const float* __restrict__ tail, const float* __restrict__ acsb,
                              const float* __restrict__ csum, const int* __restrict__ mor0,
                              const int* __restrict__ mor1, float* __restrict__ spart)
{
    const int z = blockIdx.z;
    const u16* zxp = zxb + (size_t)z * L_SEQ * 512;
    const float* dtbp = dtb + (size_t)z * L_SEQ * 4;
    const float* tl = tail + (size_t)z * L_SEQ * 12;
    const float* acsp = acsb + (size_t)z * L_SEQ * 4;
    const float* csp = csum + (size_t)z * NCH * 4;
    const int* mor = z ? mor1 : mor0;
    float* spp = spart + (size_t)z * NCH * 4096;

    __shared__ float coef[64][16];
    __shared__ int posL[64];
    const int c = blockIdx.x, q = blockIdx.y;
    const int tid = threadIdx.x;
    {
        const int l_loc = tid >> 2, h = tid & 3;
        const int gl = c * 256 + q * 64 + l_loc;
        const int pos = (gl < L_SEQ) ? mor[gl] : 0;
        float4 Bv = make_float4(0.f, 0.f, 0.f, 0.f);
        float e = 0.f;
        if (gl < L_SEQ) {
            Bv = *(const float4*)(tl + (size_t)pos * 12);
            e = exp2f(csp[c * 4 + h] - acsp[(size_t)gl * 4 + h]) * dtbp[(size_t)gl * 4 + h];
        }
        *(float4*)&coef[l_loc][h * 4] = make_float4(Bv.x * e, Bv.y * e, Bv.z * e, Bv.w * e);
        if (h == 0) posL[l_loc] = pos;
    }
    __syncthreads();
    const int h = tid >> 6;
    f32x4 acc = (f32x4){0.f, 0.f, 0.f, 0.f};
#pragma unroll 4
    for (int j = 0; j < 64; ++j) {
        const int gl = c * 256 + q * 64 + j;
        float xs = 0.f;
        if (gl < L_SEQ) xs = bf2f(zxp[(size_t)posL[j] * 512 + 256 + tid]);
        float4 cf = *(const float4*)&coef[j][h * 4];
        acc[0] += cf.x * xs; acc[1] += cf.y * xs;
        acc[2] += cf.z * xs; acc[3] += cf.w * xs;
    }
    *(f32x4*)(spp + ((size_t)(c * 4 + q) * 256 + tid) * 4) = acc;
}

// ---------------------------------------------------------------------------
// Inter-chunk scan with fused q-reduction.
// ---------------------------------------------------------------------------
__launch_bounds__(256)
__global__ void chunkscan_k(const float* __restrict__ csum, const float* __restrict__ spart,
                            float* __restrict__ prev)
{
    const int z = blockIdx.y;
    const float* csp = csum + (size_t)z * NCH * 4;
    const float* spp = spart + (size_t)z * NCH * 4096;
    float* prp = prev + (size_t)z * NCH * 1024;

    const int h = blockIdx.x;
    const int tid = threadIdx.x;
    __shared__ float ecs[NCH];
    if (tid < NCH) ecs[tid] = exp2f(csp[tid * 4 + h]);
    __syncthreads();
    float run = 0.f;
#pragma unroll 2
    for (int c = 0; c < NCH; ++c) {
        const float* sp = spp + (size_t)(c * 4) * 1024 + h * 256 + tid;
        float s = sp[0] + sp[1024] + sp[2048] + sp[3072];
        prp[(size_t)c * 1024 + h * 256 + tid] = run;
        run = run * ecs[c] + s;
    }
}

// ---------------------------------------------------------------------------
// MFMA per-chunk output v4.1 (exp-factored).
// ---------------------------------------------------------------------------
__launch_bounds__(1024, 4)
__global__ void ychunk4_k(const u16* __restrict__ zxb, const float* __restrict__ tail,
                          const float* __restrict__ dtb, const float* __restrict__ acsb,
                          const float* __restrict__ prev, const float* __restrict__ Dv0,
                          const float* __restrict__ Dv1, const int* __restrict__ mor0,
                          const int* __restrict__ mor1, u16* __restrict__ cat)
{
    const int z = blockIdx.z;
    const u16* zxp = zxb + (size_t)z * L_SEQ * 512;
    const float* tl = tail + (size_t)z * L_SEQ * 12;
    const float* dtbp = dtb + (size_t)z * L_SEQ * 4;
    const float* acsp = acsb + (size_t)z * L_SEQ * 4;
    const float* prp = prev + (size_t)z * NCH * 1024;
    const float* Dv = z ? Dv1 : Dv0;
    const int* mor = z ? mor1 : mor0;
    const int catOff = z * 256;

    __shared__ __align__(16) u16 Xt[64 * 256];
    __shared__ __align__(16) u16 Xp[64 * 40];
    __shared__ float4 sBdt[256];
    __shared__ float4 sC[256];
    __shared__ float  sA2[256];
    __shared__ int    morL[256];

    const int c = blockIdx.x, h = blockIdx.y;
    const int tid = threadIdx.x;
    const int lane = tid & 63, w = tid >> 6;     // w = 0..15

    if (tid < 256) {
        const int s = tid, gl = c * 256 + s;
        const int pos = (gl < L_SEQ) ? mor[gl] : 0;
        morL[s] = pos;
        if (gl < L_SEQ) {
            const float* tr = tl + (size_t)pos * 12;
            float4 B4 = *(const float4*)tr;
            float4 C4v = *(const float4*)(tr + 4);
            float dt = dtbp[(size_t)gl * 4 + h];
            sBdt[s] = make_float4(B4.x * dt, B4.y * dt, B4.z * dt, B4.w * dt);
            sC[s] = C4v;
            sA2[s] = acsp[(size_t)gl * 4 + h];
        } else {
            sBdt[s] = make_float4(0.f, 0.f, 0.f, 0.f);
            sC[s] = make_float4(0.f, 0.f, 0.f, 0.f);
            sA2[s] = 0.f;
        }
    } else if (tid < 320) {
        int i = tid - 256;
        float4 pv = *(const float4*)(prp + (size_t)c * 1024 + h * 256 + i * 4);
        u32 w0 = cvtpk(pv.x, pv.y), w1 = cvtpk(pv.z, pv.w);
        uint4* row = (uint4*)((char*)Xp + i * 80);
        row[0] = make_uint4(w0, w1, 0u, 0u);
        row[1] = make_uint4(0u, 0u, 0u, 0u);
        row[2] = make_uint4(0u, 0u, 0u, 0u);
        row[3] = make_uint4(0u, 0u, 0u, 0u);
    }
    __syncthreads();

    if (tid < 256) {
        const int s = tid;
        float es = exp2f(sA2[s & ~7] - sA2[s]);
        float4 b4 = sBdt[s];
        sBdt[s] = make_float4(b4.x * es, b4.y * es, b4.z * es, b4.w * es);
    }
    {
        const int p = lane;
        const size_t colOff = 256 + h * 64 + p;
#pragma unroll
        for (int jq = 0; jq < 2; ++jq) {
            const int s0 = w * 16 + jq * 8;
            u32 wd[4];
#pragma unroll
            for (int q2 = 0; q2 < 4; ++q2) {
                int sIdx = s0 + q2 * 2;
                int gl0 = c * 256 + sIdx;
                u32 lo = (gl0     < L_SEQ) ? (u32)zxp[(size_t)morL[sIdx] * 512 + colOff] : 0u;
                u32 hi = (gl0 + 1 < L_SEQ) ? (u32)zxp[(size_t)morL[sIdx + 1] * 512 + colOff] : 0u;
                wd[q2] = lo | (hi << 16);
            }
            u32 off = (u32)(p * 512 + s0 * 2) ^ (u32)((p & 15) << 4);
            *(uint4*)((char*)Xt + off) = make_uint4(wd[0], wd[1], wd[2], wd[3]);
        }
    }
    __syncthreads();

    const int rl15 = lane & 15, kg = lane >> 4;
    const int R = w * 16;
    const int km = w >> 1;
    const float Dh = Dv[h];
    const int lrow = R + rl15;
    const float4 C4 = sC[lrow];
    const float al2 = sA2[lrow];

    f32x4 acc[4];
#pragma unroll
    for (int n = 0; n < 4; ++n) acc[n] = (f32x4){0.f, 0.f, 0.f, 0.f};

    for (int ks = 0; ks <= km; ++ks) {
        const int s0 = ks * 32 + kg * 8;
        short8 bf[4];
#pragma unroll
        for (int n = 0; n < 4; ++n) {
            int col = n * 16 + rl15;
            u32 off = (u32)(col * 512 + ks * 64 + kg * 16) ^ (u32)((col & 15) << 4);
            bf[n] = *(const short8*)((const char*)Xt + off);
        }
        const float eL = exp2f(al2 - sA2[s0]);
        float4 Bv[8];
#pragma unroll
        for (int j = 0; j < 8; ++j) Bv[j] = sBdt[s0 + j];
        float vv[8];
        if (ks < km) {
#pragma unroll
            for (int j = 0; j < 8; ++j) {
                float dot = C4.x * Bv[j].x + C4.y * Bv[j].y
                          + C4.z * Bv[j].z + C4.w * Bv[j].w;
                vv[j] = dot * eL;
            }
        } else {
#pragma unroll
            for (int j = 0; j < 8; ++j) {
                int s = s0 + j;
                float dot = C4.x * Bv[j].x + C4.y * Bv[j].y
                          + C4.z * Bv[j].z + C4.w * Bv[j].w;
                float v = dot * eL;
                v = (s <= lrow) ? v : 0.f;
                vv[j] = (s == lrow) ? v + Dh : v;
            }
        }
        union { u32 wd[4]; short8 v; } aw;
#pragma unroll
        for (int q2 = 0; q2 < 4; ++q2) aw.wd[q2] = cvtpk(vv[2 * q2], vv[2 * q2 + 1]);
#pragma unroll
        for (int n = 0; n < 4; ++n)
            acc[n] = __builtin_amdgcn_mfma_f32_16x16x32_bf16(aw.v, bf[n], acc[n], 0, 0, 0);
    }
    {
        short8 bp[4];
#pragma unroll
        for (int n = 0; n < 4; ++n) {
            int col = n * 16 + rl15;
            bp[n] = *(const short8*)((const char*)Xp + col * 80 + kg * 16);
        }
        float ea = exp2f(al2);
        union { u32 wd[4]; short8 v; } aw;
        aw.wd[0] = (kg == 0) ? cvtpk(ea * C4.x, ea * C4.y) : 0u;
        aw.wd[1] = (kg == 0) ? cvtpk(ea * C4.z, ea * C4.w) : 0u;
        aw.wd[2] = 0u; aw.wd[3] = 0u;
#pragma unroll
        for (int n = 0; n < 4; ++n)
            acc[n] = __builtin_amdgcn_mfma_f32_16x16x32_bf16(aw.v, bp[n], acc[n], 0, 0, 0);
    }

#pragma unroll
    for (int r = 0; r < 4; ++r) {
        const int row = R + kg * 4 + r;
        const int gl = c * 256 + row;
        if (gl >= L_SEQ) continue;
        const int pos = morL[row];
        const size_t zbase = (size_t)pos * 512 + h * 64;
        u16* orow = cat + (size_t)pos * 512 + catOff + h * 64;
#pragma unroll
        for (int n = 0; n < 4; ++n) {
            const int col = n * 16 + rl15;
            float zs = bf2f(zxp[zbase + col]);
            float y = acc[n][r] * zs;
            orow[col] = (u16)cvtpk(y, y);
        }
    }
}

// ---------------------------------------------------------------------------
extern "C" void kernel_launch(void* const* d_in, const int* in_sizes, int n_in,
                              void* d_out, int out_size, void* d_ws, size_t ws_size,
                              hipStream_t stream)
{
    const float* x      = (const float*)d_in[0];
    const float* W_in0  = (const float*)d_in[1];
    const float* W_in1  = (const float*)d_in[2];
    const float* dt_b0  = (const float*)d_in[3];
    const float* dt_b1  = (const float*)d_in[4];
    const float* A_log0 = (const float*)d_in[5];
    const float* A_log1 = (const float*)d_in[6];
    const float* Dv0    = (const float*)d_in[7];
    const float* Dv1    = (const float*)d_in[8];
    const float* W_out  = (const float*)d_in[9];
    const float* ln_g   = (const float*)d_in[10];
    const float* ln_b   = (const float*)d_in[11];
    const int*   mor0   = (const int*)d_in[12];
    const int*   mor1   = (const int*)d_in[13];

    char* ws = (char*)d_ws;
    size_t off = 0;
    auto alloc = [&](size_t bytes) { char* p = ws + off; off += (bytes + 255) & ~(size_t)255; return p; };
    u16*   xt    = (u16*)  alloc((size_t)MPAD * 256 * 2);
    u16*   zxb   = (u16*)  alloc((size_t)2 * L_SEQ * 512 * 2);
    u16*   cat   = (u16*)  alloc((size_t)MPAD * 512 * 2);
    float* tail  = (float*)alloc((size_t)2 * L_SEQ * 12 * 4);
    u16*   wbufI = (u16*)  alloc((size_t)1280 * 256 * 2);
    u16*   wbufO = (u16*)  alloc((size_t)256 * 512 * 2);
    float* dtb   = (float*)alloc((size_t)2 * L_SEQ * 4 * 4);
    float* acsb  = (float*)alloc((size_t)2 * L_SEQ * 4 * 4);
    float* csum  = (float*)alloc((size_t)2 * NCH * 4 * 4);
    float* spart = (float*)alloc((size_t)2 * NCH * 4096 * 4);
    float* prev  = (float*)alloc((size_t)2 * NCH * 1024 * 4);

    convpad2_k<<<dim3(640, 2), 256, 0, stream>>>(W_in0, W_in1, wbufI, 524, 256, (size_t)640 * 256);
    convpad2_k<<<dim3(256, 1), 256, 0, stream>>>(W_out, W_out, wbufO, 256, 512, 0);
    xpose_k<<<507, 256, 0, stream>>>(x, xt);
    zero2_k<<<dim3(112, 1), 256, 0, stream>>>(xt + (size_t)L_SEQ * 256, 0, 112 * 256);

    // merged in-proj: M=32512, N=1280, K=256
    wsgemm_k<1, 256, 2, 5, 102><<<510, 512, 0, stream>>>(xt, wbufI, nullptr, zxb, tail);

    prep_k<<<dim3(NCH, 2), 256, 0, stream>>>(tail, dt_b0, dt_b1, A_log0, A_log1,
                                             mor0, mor1, dtb, acsb, csum);
    states_part_k<<<dim3(NCH, 4, 2), 256, 0, stream>>>(zxb, dtb, tail, acsb, csum,
                                                       mor0, mor1, spart);
    chunkscan_k<<<dim3(4, 2), 256, 0, stream>>>(csum, spart, prev);
    ychunk4_k<<<dim3(NCH, NH, 2), 1024, 0, stream>>>(zxb, tail, dtb, acsb, prev,
                                                     Dv0, Dv1, mor0, mor1, cat);

    zero2_k<<<dim3(224, 1), 256, 0, stream>>>(cat + (size_t)L_SEQ * 512, 0, 112 * 512);
    // out-proj + fused LayerNorm + transpose: M=32512, N=256, K=512
    wsgemmLN_k<508><<<508, 1024, 0, stream>>>(cat, wbufO, ln_g, ln_b, (float*)d_out);
}